// Round 19
// baseline (531.132 us; speedup 1.0000x reference)
//
#include <hip/hip_runtime.h>

typedef __bf16 bf16;
typedef __bf16 bf16x8 __attribute__((ext_vector_type(8)));
typedef __bf16 bf16x4 __attribute__((ext_vector_type(4)));
typedef float  f32x4  __attribute__((ext_vector_type(4)));

#define MFMA_BF16(a, b, c) __builtin_amdgcn_mfma_f32_16x16x32_bf16(a, b, c, 0, 0, 0)

constexpr int cB    = 2;
constexpr int cH    = 96;
constexpr int cW    = 320;
constexpr int cC    = 128;
constexpr int cNPIX = cH * cW;          // 30720
constexpr int cNTOK = cB * cNPIX;       // 61440
constexpr int cCS   = 224;              // combined outlook stride (v 0..127, attn 128..208)

// ---------------------------------------------------------------------------
// Weight transpose+convert: fp32 W (K x M) -> bf16 Wt (M x K)
// ---------------------------------------------------------------------------
struct WJob  { const float* src; bf16* dst; int K; int M; };
struct WJobs { WJob j[19]; };

__global__ __launch_bounds__(256) void k_wt(WJobs jobs)
{
    __shared__ float tile[32][33];
    const WJob jb = jobs.j[blockIdx.z];
    int k0 = blockIdx.y * 32, m0 = blockIdx.x * 32;
    if (k0 >= jb.K || m0 >= jb.M) return;
    int tx = threadIdx.x, ty = threadIdx.y;
#pragma unroll
    for (int i = 0; i < 32; i += 8) {
        int kk = k0 + ty + i, mm = m0 + tx;
        tile[ty + i][tx] = (kk < jb.K && mm < jb.M) ? jb.src[(size_t)kk * jb.M + mm] : 0.f;
    }
    __syncthreads();
#pragma unroll
    for (int i = 0; i < 32; i += 8) {
        int mm = m0 + ty + i, kk = k0 + tx;
        if (mm < jb.M && kk < jb.K)
            jb.dst[(size_t)mm * jb.K + kk] = (bf16)tile[tx][ty + i];
    }
}

__global__ __launch_bounds__(256) void k_dwt(const float* s0, const float* s1, const float* s2,
                                             float* d0, float* d1, float* d2)
{
    const float* s = blockIdx.x == 0 ? s0 : (blockIdx.x == 1 ? s1 : s2);
    float*       d = blockIdx.x == 0 ? d0 : (blockIdx.x == 1 ? d1 : d2);
    for (int i = threadIdx.x; i < 512 * 9; i += 256) {
        int c = i / 9, tap = i - c * 9;
        d[tap * 512 + c] = s[i];
    }
}

__global__ __launch_bounds__(256) void k_postab(float* __restrict__ yt, float* __restrict__ xt)
{
    int i = blockIdx.x * 256 + threadIdx.x;
    const float TWO_PI = 6.283185307179586f;
    const float KSC = -9.210340371976184f / 32.f;
    if (i < 96 * 64) {
        int h = i >> 6, c = i & 63;
        float p = (float)(h + 1) * (TWO_PI / (96.f + 1e-6f));
        float val = p * expf((float)(c >> 1) * KSC);
        yt[i] = (c & 1) ? cosf(val) : sinf(val);
    }
    if (i < 320 * 64) {
        int w = i >> 6, c = i & 63;
        float p = (float)(w + 1) * (TWO_PI / (320.f + 1e-6f));
        float val = p * expf((float)(c >> 1) * KSC);
        xt[i] = (c & 1) ? cosf(val) : sinf(val);
    }
}

// ---------------------------------------------------------------------------
// Input transpose (B, C=256, HW) -> (B, HW, C) bf16
// ---------------------------------------------------------------------------
__global__ __launch_bounds__(256) void k_chw2hwc(const float* __restrict__ in,
                                                 bf16* __restrict__ out)
{
    __shared__ float tile[32][33];
    const int Cc = 256;
    int s0 = blockIdx.x * 32;
    int c0 = blockIdx.y * 32;
    int b  = blockIdx.z;
    const float* ip = in  + (size_t)b * Cc * cNPIX;
    bf16*        op = out + (size_t)b * cNPIX * Cc;
    int tx = threadIdx.x, ty = threadIdx.y;
#pragma unroll
    for (int i = 0; i < 32; i += 8)
        tile[ty + i][tx] = ip[(size_t)(c0 + ty + i) * cNPIX + s0 + tx];
    __syncthreads();
#pragma unroll
    for (int i = 0; i < 32; i += 8)
        op[(size_t)(s0 + ty + i) * Cc + c0 + tx] = (bf16)tile[tx][ty + i];
}

// ---------------------------------------------------------------------------
// K=128 single-shot GEMM. QKVS: -1 plain; 0/1 QKV (shift folded);
// 2 = combined outlook (M=224: cols 0..127 v, 128..208 attn; W rows >=209 zero).
// ---------------------------------------------------------------------------
template<int QKVS>
__global__ __launch_bounds__(256) void k_gemm128(const bf16* __restrict__ A,
                                                 const bf16* __restrict__ Wt,
                                                 const float* __restrict__ bias,
                                                 bf16* __restrict__ outB, int M,
                                                 bf16* __restrict__ vtb,
                                                 bf16* __restrict__ ksb)
{
    __shared__ bf16 As[128][136];
    __shared__ bf16 Sb[64][136];

    const int NS = (QKVS == 2) ? 2 : (M >> 7);
    const int l  = blockIdx.x;
    const int r8 = l % (8 * NS);
    const int qq = l / (8 * NS);
    const int bm = (qq * 8 + (r8 & 7)) * 128;
    const int bn = (r8 >> 3) * 128;

    const int t = threadIdx.x;
    const int lane = t & 63, wid = t >> 6;
    const int wm = (wid >> 1) * 64, wn = (wid & 1) * 64;
    const int lr = lane & 15, lg = lane >> 4;

    bf16x8 zrow;
#pragma unroll
    for (int j = 0; j < 8; ++j) zrow[j] = (bf16)0.f;

    bool okw[4];
#pragma unroll
    for (int nf = 0; nf < 4; ++nf)
        okw[nf] = (QKVS != 2) || (bn + wn + nf * 16 + lr < 209);

    const bf16* wp = Wt + (size_t)(bn + wn + lr) * 128 + lg * 8;
    bf16x8 bwA[4], bwB[4];
#pragma unroll
    for (int nf = 0; nf < 4; ++nf)
        bwA[nf] = okw[nf] ? *(const bf16x8*)(wp + (size_t)(nf * 16) * 128) : zrow;

#pragma unroll
    for (int i = 0; i < 8; ++i) {
        int o = i * 256 + t;
        int row = o >> 4, cg = (o & 15) * 8;
        *(bf16x8*)&As[row][cg] = *(const bf16x8*)(A + (size_t)(bm + row) * 128 + cg);
    }
    __syncthreads();

    const f32x4 zero4 = {0.f, 0.f, 0.f, 0.f};
    f32x4 acc[4][4];
#pragma unroll
    for (int i = 0; i < 4; ++i)
#pragma unroll
        for (int j = 0; j < 4; ++j) acc[i][j] = zero4;

#pragma unroll
    for (int ks = 0; ks < 4; ++ks) {
        const bf16x8* cur = (ks & 1) ? bwB : bwA;
        bf16x8*       nxt = (ks & 1) ? bwA : bwB;
        if (ks < 3) {
#pragma unroll
            for (int nf = 0; nf < 4; ++nf)
                nxt[nf] = okw[nf] ? *(const bf16x8*)(wp + (size_t)(nf * 16) * 128 + (ks + 1) * 32) : zrow;
        }
        bf16x8 af[4];
#pragma unroll
        for (int mf = 0; mf < 4; ++mf)
            af[mf] = *(const bf16x8*)&As[wm + mf*16 + lr][ks*32 + lg*8];
        __builtin_amdgcn_s_setprio(1);
#pragma unroll
        for (int mf = 0; mf < 4; ++mf)
#pragma unroll
            for (int nf = 0; nf < 4; ++nf)
                acc[mf][nf] = MFMA_BF16(af[mf], cur[nf], acc[mf][nf]);
        __builtin_amdgcn_s_setprio(0);
    }

    const bool vpart = (QKVS == 0 || QKVS == 1) && (bn == 256);
    const bool kpart = (QKVS == 0 || QKVS == 1) && (bn == 128);
    if (!vpart) {
#pragma unroll
        for (int half = 0; half < 2; ++half) {
            __syncthreads();
            if ((wid >> 1) == half) {
#pragma unroll
                for (int nf = 0; nf < 4; ++nf) {
                    int col = wn + nf * 16 + lr;
                    float bv = bias ? bias[bn + col] : 0.f;
#pragma unroll
                    for (int mf = 0; mf < 4; ++mf)
#pragma unroll
                        for (int r = 0; r < 4; ++r)
                            Sb[mf * 16 + lg * 4 + r][col] = (bf16)(acc[mf][nf][r] + bv);
                }
            }
            __syncthreads();
            if (!kpart) {
                const int ldo = (QKVS == 2) ? cCS : ((QKVS >= 0) ? 128 : M);
#pragma unroll
                for (int i = 0; i < 4; ++i) {
                    int o = i * 256 + t;
                    int row = o >> 4, cg = (o & 15) * 8;
                    if (QKVS == 2 && bn + cg + 8 > cCS) continue;
                    *(bf16x8*)(outB + (size_t)(bm + half * 64 + row) * ldo + bn + cg) =
                        *(const bf16x8*)&Sb[row][cg];
                }
            } else {
#pragma unroll
                for (int i = 0; i < 4; ++i) {
                    int o = i * 256 + t;
                    int row = o >> 4, cg = (o & 15) * 8;
                    int gt = bm + half * 64 + row;
                    int b_ = gt / cNPIX, hw = gt - b_ * cNPIX;
                    int h = hw / cW, w = hw - (hw / cW) * cW;
                    int h0 = (QKVS == 1) ? ((h + 90) % 96)  : h;
                    int w0 = (QKVS == 1) ? ((w + 300) % 320) : w;
                    int nh = h0 / 12, kh = h0 - nh * 12;
                    int nw = w0 / 40, kw = w0 - nw * 40;
                    size_t krow = (size_t)((b_ * 64 + nh * 8 + nw) * 480 + kh * 40 + kw);
                    *(bf16x8*)(ksb + krow * 128 + cg) = *(const bf16x8*)&Sb[row][cg];
                }
            }
        }
    } else {
        const int lr_ = t & 15, cg_ = t >> 4;
        const int gt = bm + lr_ * 8;
        const int b_ = gt / cNPIX, hw = gt % cNPIX;
        const int h = hw / cW, w = hw % cW;
        const int h0 = (QKVS == 1) ? ((h + 90) % 96) : h;
        const int nh = h0 / 12, kh = h0 - nh * 12;
#pragma unroll
        for (int cp = 0; cp < 2; ++cp) {
            __syncthreads();
            if ((wid & 1) == cp) {
#pragma unroll
                for (int nf = 0; nf < 4; ++nf) {
                    int cl = nf * 16 + lr;
#pragma unroll
                    for (int mf = 0; mf < 4; ++mf)
#pragma unroll
                        for (int r = 0; r < 4; ++r)
                            Sb[cl][wm + mf * 16 + lg * 4 + r] = (bf16)acc[mf][nf][r];
                }
            }
            __syncthreads();
#pragma unroll
            for (int i = 0; i < 4; ++i) {
                int chl = cg_ + 16 * i;
                int ch  = cp * 64 + chl;
                bf16x8 e = *(const bf16x8*)&Sb[chl][lr_ * 8];
#pragma unroll
                for (int hi = 0; hi < 2; ++hi) {
                    int wv = (QKVS == 1) ? ((w + hi * 4 + 300) % 320) : (w + hi * 4);
                    int nw = wv / 40, kw = wv - nw * 40;
                    bf16* dst = vtb + ((size_t)((b_ * 64 + nh * 8 + nw) * 128 + ch)) * 480 + kh * 40 + kw;
                    bf16x4 hv;
#pragma unroll
                    for (int j = 0; j < 4; ++j) hv[j] = e[hi * 4 + j];
                    *(bf16x4*)dst = hv;
                }
            }
        }
    }
}

// ---------------------------------------------------------------------------
// Generic k-loop GEMM, M=128: 1-barrier dbuf K-loop, bf16 residual stream.
// ---------------------------------------------------------------------------
template<bool OUTBF, bool RELU, bool RES, bool POS, bool LNOUT, bool TOUT>
__global__ __launch_bounds__(256) void k_gemm_res(const bf16* __restrict__ A,
                                                  const bf16* __restrict__ Wt,
                                                  const float* __restrict__ bias,
                                                  const bf16* __restrict__ resB,
                                                  bf16* __restrict__ outFB,
                                                  bf16* __restrict__ outB,
                                                  float* __restrict__ outT,
                                                  int K,
                                                  const float* __restrict__ ytab,
                                                  const float* __restrict__ xtab,
                                                  const float* __restrict__ lng,
                                                  const float* __restrict__ lnb,
                                                  bf16* __restrict__ xnbO)
{
    __shared__ bf16 As[2][128][40];
    __shared__ bf16 Bs[2][128][40];
    __shared__ float Sf[64][136];

    const int bm = blockIdx.x * 128;
    const int t = threadIdx.x;
    const int lane = t & 63, wid = t >> 6;
    const int wm = (wid >> 1) * 64, wn = (wid & 1) * 64;
    const int lr = lane & 15, lg = lane >> 4;

    const int r0 = t >> 2,          kg0 = (t & 3) * 8;
    const int r1 = (t + 256) >> 2,  kg1 = ((t + 256) & 3) * 8;

    const int nks = K >> 5;

    auto loadAW = [&](int k0, bf16x8* ra, bf16x8* rw) {
        ra[0] = *(const bf16x8*)(A  + (size_t)(bm + r0) * K + k0 + kg0);
        ra[1] = *(const bf16x8*)(A  + (size_t)(bm + r1) * K + k0 + kg1);
        rw[0] = *(const bf16x8*)(Wt + (size_t)r0 * K + k0 + kg0);
        rw[1] = *(const bf16x8*)(Wt + (size_t)r1 * K + k0 + kg1);
    };

    bf16x8 ra[2], rw[2];
    loadAW(0, ra, rw);
    *(bf16x8*)&As[0][r0][kg0] = ra[0];
    *(bf16x8*)&As[0][r1][kg1] = ra[1];
    *(bf16x8*)&Bs[0][r0][kg0] = rw[0];
    *(bf16x8*)&Bs[0][r1][kg1] = rw[1];
    if (nks > 1) loadAW(32, ra, rw);

    const f32x4 zero4 = {0.f, 0.f, 0.f, 0.f};
    f32x4 acc[4][4];
#pragma unroll
    for (int i = 0; i < 4; ++i)
#pragma unroll
        for (int j = 0; j < 4; ++j) acc[i][j] = zero4;

    for (int ks = 0; ks < nks; ++ks) {
        const int cur = ks & 1;
        __syncthreads();
        if (ks + 1 < nks) {
            *(bf16x8*)&As[cur ^ 1][r0][kg0] = ra[0];
            *(bf16x8*)&As[cur ^ 1][r1][kg1] = ra[1];
            *(bf16x8*)&Bs[cur ^ 1][r0][kg0] = rw[0];
            *(bf16x8*)&Bs[cur ^ 1][r1][kg1] = rw[1];
            if (ks + 2 < nks) loadAW((ks + 2) * 32, ra, rw);
        }
        bf16x8 af[4], bf[4];
#pragma unroll
        for (int mf = 0; mf < 4; ++mf)
            af[mf] = *(const bf16x8*)&As[cur][wm + mf*16 + lr][lg * 8];
#pragma unroll
        for (int nf = 0; nf < 4; ++nf)
            bf[nf] = *(const bf16x8*)&Bs[cur][wn + nf*16 + lr][lg * 8];
        __builtin_amdgcn_s_setprio(1);
#pragma unroll
        for (int mf = 0; mf < 4; ++mf)
#pragma unroll
            for (int nf = 0; nf < 4; ++nf)
                acc[mf][nf] = MFMA_BF16(af[mf], bf[nf], acc[mf][nf]);
        __builtin_amdgcn_s_setprio(0);
    }
    __syncthreads();

    if (OUTBF) {
        bf16 (*Sb)[136] = (bf16(*)[136])Sf;
#pragma unroll
        for (int nf = 0; nf < 4; ++nf) {
            int col = wn + nf * 16 + lr;
            float bv = bias ? bias[col] : 0.f;
#pragma unroll
            for (int mf = 0; mf < 4; ++mf)
#pragma unroll
                for (int r = 0; r < 4; ++r) {
                    float vv = acc[mf][nf][r] + bv;
                    if (RELU) vv = fmaxf(vv, 0.f);
                    Sb[wm + mf * 16 + lg * 4 + r][col] = (bf16)vv;
                }
        }
        __syncthreads();
#pragma unroll
        for (int i = 0; i < 8; ++i) {
            int o = i * 256 + t;
            int row = o >> 4, cg = (o & 15) * 8;
            *(bf16x8*)(outB + (size_t)(bm + row) * 128 + cg) = *(const bf16x8*)&Sb[row][cg];
        }
    } else {
        const int b_   = bm / cNPIX;
        const int hw0  = bm - b_ * cNPIX;
        for (int half = 0; half < 2; ++half) {
            __syncthreads();
            if ((wid >> 1) == half) {
#pragma unroll
                for (int nf = 0; nf < 4; ++nf) {
                    int col = wn + nf * 16 + lr;
                    float bv = bias ? bias[col] : 0.f;
#pragma unroll
                    for (int mf = 0; mf < 4; ++mf)
#pragma unroll
                        for (int r = 0; r < 4; ++r)
                            Sf[mf * 16 + lg * 4 + r][col] = acc[mf][nf][r] + bv;
                }
            }
            __syncthreads();
            if (!TOUT) {
#pragma unroll
                for (int i = 0; i < 8; ++i) {
                    int o = i * 256 + t;
                    int row = o >> 5, cq = (o & 31) * 4;
                    int grow = bm + half * 64 + row;
                    float4 v = *(const float4*)&Sf[row][cq];
                    if (POS) {
                        int hw = grow % cNPIX;
                        int h = hw / cW, w = hw - (hw / cW) * cW;
                        float4 p = (cq < 64) ? *(const float4*)(ytab + (h << 6) + cq)
                                             : *(const float4*)(xtab + (w << 6) + cq - 64);
                        v.x += p.x; v.y += p.y; v.z += p.z; v.w += p.w;
                    }
                    if (RES) {
                        bf16x4 rr = *(const bf16x4*)(resB + (size_t)grow * 128 + cq);
                        v.x += (float)rr[0]; v.y += (float)rr[1];
                        v.z += (float)rr[2]; v.w += (float)rr[3];
                    }
                    if (LNOUT) {
                        float s  = v.x + v.y + v.z + v.w;
                        float sq = v.x*v.x + v.y*v.y + v.z*v.z + v.w*v.w;
#pragma unroll
                        for (int mk = 1; mk < 32; mk <<= 1) {
                            s  += __shfl_xor(s,  mk);
                            sq += __shfl_xor(sq, mk);
                        }
                        float mu = s * (1.f / 128.f);
                        float rs = rsqrtf(sq * (1.f / 128.f) - mu * mu + 1e-5f);
                        float4 g4 = *(const float4*)(lng + cq);
                        float4 b4 = *(const float4*)(lnb + cq);
                        bf16x4 xo;
                        xo[0] = (bf16)((v.x - mu) * rs * g4.x + b4.x);
                        xo[1] = (bf16)((v.y - mu) * rs * g4.y + b4.y);
                        xo[2] = (bf16)((v.z - mu) * rs * g4.z + b4.z);
                        xo[3] = (bf16)((v.w - mu) * rs * g4.w + b4.w);
                        *(bf16x4*)(xnbO + (size_t)grow * 128 + cq) = xo;
                    }
                    bf16x4 fv;
                    fv[0] = (bf16)v.x; fv[1] = (bf16)v.y;
                    fv[2] = (bf16)v.z; fv[3] = (bf16)v.w;
                    *(bf16x4*)(outFB + (size_t)grow * 128 + cq) = fv;
                }
            } else {
#pragma unroll
                for (int i = 0; i < 8; ++i) {
                    int o = i * 256 + t;
                    int row = o >> 5, cq = (o & 31) * 4;
                    int grow = bm + half * 64 + row;
                    float4 v = *(const float4*)&Sf[row][cq];
                    bf16x4 rr = *(const bf16x4*)(resB + (size_t)grow * 128 + cq);
                    v.x += (float)rr[0]; v.y += (float)rr[1];
                    v.z += (float)rr[2]; v.w += (float)rr[3];
                    *(float4*)&Sf[row][cq] = v;
                }
                __syncthreads();
                const int lane16 = t & 15;
#pragma unroll
                for (int p = 0; p < 8; ++p) {
                    int col = p * 16 + (t >> 4);
                    float4 v;
                    v.x = Sf[lane16 * 4 + 0][col];
                    v.y = Sf[lane16 * 4 + 1][col];
                    v.z = Sf[lane16 * 4 + 2][col];
                    v.w = Sf[lane16 * 4 + 3][col];
                    *(float4*)(outT + ((size_t)(b_ * 128 + col)) * cNPIX
                               + hw0 + half * 64 + lane16 * 4) = v;
                }
            }
        }
    }
}

// ---------------------------------------------------------------------------
// Outlook fused gather over the combined buffer (stride 224: v@0, attn@128).
// ---------------------------------------------------------------------------
__global__ __launch_bounds__(256) void k_olk_gather(const bf16* __restrict__ comb,
                                                    bf16* __restrict__ y)
{
    __shared__ bf16  Ls[100][136];
    __shared__ float pr[16][84];
    __shared__ float coef[16][26];

    const int t  = threadIdx.x;
    const int px = t >> 4;
    const int j  = t & 15;
    const int pix0 = blockIdx.x * 16;
    const int b   = pix0 / cNPIX;
    const int hw0 = pix0 % cNPIX;
    const int h   = hw0 / cW, w0 = hw0 % cW;
    const int pix = pix0 + px;
    const int w   = w0 + px;

    const size_t bbase = (size_t)b * cNPIX;

    for (int e = px; e < 100; e += 16) {
        const int a  = e / 20, cc = e - a * 20;
        const int sh = h + a - 2, sw = w0 + cc - 2;
        bf16x8 val;
        if ((unsigned)sh < (unsigned)cH && (unsigned)sw < (unsigned)cW) {
            val = *(const bf16x8*)(comb + (bbase + (size_t)sh * cW + sw) * cCS + j * 8);
        } else {
#pragma unroll
            for (int q = 0; q < 8; ++q) val[q] = (bf16)0.f;
        }
        *(bf16x8*)&Ls[e][j * 8] = val;
    }

    if (j < 9) {
        const int p  = j;
        const int pi = p / 3, pj = p - pi * 3;
        const int hh = h + 1 - pi, ww = w + 1 - pj;
        float prv[9];
        if ((unsigned)hh < (unsigned)cH && (unsigned)ww < (unsigned)cW) {
            const size_t row = bbase + (size_t)hh * cW + ww;
            const bf16* arow = comb + row * cCS + 128 + p * 9;
            float lg[9];
            float m = 0.f;
#pragma unroll
            for (int q = 0; q < 9; ++q) { lg[q] = (float)arow[q]; m = fmaxf(m, lg[q]); }
            float se = 0.f;
#pragma unroll
            for (int q = 0; q < 9; ++q) { prv[q] = __expf(lg[q] - m); se += prv[q]; }
            float inv = 1.f / (se + __expf(-m));
#pragma unroll
            for (int q = 0; q < 9; ++q) prv[q] *= inv;
        } else {
#pragma unroll
            for (int q = 0; q < 9; ++q) prv[q] = 0.f;
        }
#pragma unroll
        for (int q = 0; q < 9; ++q) pr[px][p * 9 + q] = prv[q];
    }
    __syncthreads();

    for (int d = j; d < 25; d += 16) {
        const int a  = d / 5, bb = d - a * 5;
        float s = 0.f;
#pragma unroll
        for (int pi = 0; pi < 3; ++pi) {
            const int qi = pi + a - 2;
            if ((unsigned)qi >= 3u) continue;
#pragma unroll
            for (int pj = 0; pj < 3; ++pj) {
                const int qj = pj + bb - 2;
                if ((unsigned)qj >= 3u) continue;
                s += pr[px][(pi * 3 + pj) * 9 + qi * 3 + qj];
            }
        }
        coef[px][d] = s;
    }
    __syncthreads();

    float acc[8] = {};
#pragma unroll
    for (int a = 0; a < 5; ++a) {
#pragma unroll
        for (int bb = 0; bb < 5; ++bb) {
            const float cf = coef[px][a * 5 + bb];
            const bf16x8 v8 = *(const bf16x8*)&Ls[a * 20 + px + bb][j * 8];
#pragma unroll
            for (int e = 0; e < 8; ++e) acc[e] = fmaf(cf, (float)v8[e], acc[e]);
        }
    }
    bf16x8 o8;
#pragma unroll
    for (int e = 0; e < 8; ++e) o8[e] = (bf16)acc[e];
    *(bf16x8*)(y + (size_t)pix * 128 + j * 8) = o8;
}

// ---------------------------------------------------------------------------
// Depthwise 3x3 + bias + fast GELU (unchanged).
// ---------------------------------------------------------------------------
__global__ __launch_bounds__(256) void k_dwconv_gelu(const bf16* __restrict__ h1,
                                                     const float* __restrict__ dwt,
                                                     const float* __restrict__ bdw,
                                                     bf16* __restrict__ h2)
{
    const int t   = threadIdx.x;
    const int c2  = t * 2;
    const int blk = blockIdx.x;
    const int row = blk >> 4;
    const int seg = blk & 15;
    const int bb  = row / cH, h = row % cH;
    const int w0  = seg * 20;

    float2 wgt[9];
#pragma unroll
    for (int k = 0; k < 9; ++k)
        wgt[k] = *(const float2*)(dwt + k * 512 + c2);
    if (h == 0) {
        wgt[0].x = wgt[0].y = wgt[1].x = wgt[1].y = wgt[2].x = wgt[2].y = 0.f;
    }
    if (h == cH - 1) {
        wgt[6].x = wgt[6].y = wgt[7].x = wgt[7].y = wgt[8].x = wgt[8].y = 0.f;
    }
    const float2 bias = *(const float2*)(bdw + c2);

    const size_t base = (size_t)bb * cNPIX;
    const int hm = (h == 0) ? 0 : h - 1;
    const int hp = (h == cH - 1) ? h : h + 1;
    const bf16* rp0 = h1 + (base + (size_t)hm * cW + w0) * 512 + c2;
    const bf16* rp1 = h1 + (base + (size_t)h  * cW + w0) * 512 + c2;
    const bf16* rp2 = h1 + (base + (size_t)hp * cW + w0) * 512 + c2;

    auto ldc = [&](const bf16* rp, int wofs) -> float2 {
        unsigned u = *(const unsigned*)(rp + (size_t)wofs * 512);
        float2 r;
        r.x = __uint_as_float(u << 16);
        r.y = __uint_as_float(u & 0xffff0000u);
        return r;
    };
    auto gelu = [](float x) -> float {
        float x2 = x * x;
        float z2 = fmaf(x2 * x, 0.0713548162726f, 1.5957691216057308f * x);
        float t1 = 1.f / (1.f + __expf(-z2));
        return x * t1;
    };

    float2 cm[3], c0[3], cp[3];
    if (seg == 0) {
#pragma unroll
        for (int r = 0; r < 3; ++r) { cm[r].x = 0.f; cm[r].y = 0.f; }
    } else {
        cm[0] = ldc(rp0, -1); cm[1] = ldc(rp1, -1); cm[2] = ldc(rp2, -1);
    }
    c0[0] = ldc(rp0, 0); c0[1] = ldc(rp1, 0); c0[2] = ldc(rp2, 0);

    bf16* op = h2 + (base + (size_t)h * cW + w0) * 512 + c2;

    for (int j = 0; j < 20; ++j) {
        if (j == 19 && seg == 15) {
#pragma unroll
            for (int r = 0; r < 3; ++r) { cp[r].x = 0.f; cp[r].y = 0.f; }
        } else {
            cp[0] = ldc(rp0, j + 1); cp[1] = ldc(rp1, j + 1); cp[2] = ldc(rp2, j + 1);
        }
        float a0 = bias.x, a1 = bias.y;
#pragma unroll
        for (int r = 0; r < 3; ++r) {
            a0 = fmaf(cm[r].x, wgt[r * 3 + 0].x, a0);
            a1 = fmaf(cm[r].y, wgt[r * 3 + 0].y, a1);
            a0 = fmaf(c0[r].x, wgt[r * 3 + 1].x, a0);
            a1 = fmaf(c0[r].y, wgt[r * 3 + 1].y, a1);
            a0 = fmaf(cp[r].x, wgt[r * 3 + 2].x, a0);
            a1 = fmaf(cp[r].y, wgt[r * 3 + 2].y, a1);
        }
        a0 = gelu(a0);
        a1 = gelu(a1);
        union { bf16 hh[2]; unsigned int u; } o2;
        o2.hh[0] = (bf16)a0;
        o2.hh[1] = (bf16)a1;
        *(unsigned int*)(op + (size_t)j * 512) = o2.u;
#pragma unroll
        for (int r = 0; r < 3; ++r) { cm[r] = c0[r]; c0[r] = cp[r]; }
    }
}

// ---------------------------------------------------------------------------
// Window attention (unchanged from R15: 8-wave, dbuf, 1 barrier/tile).
// ---------------------------------------------------------------------------
template<bool SHIFT>
__global__ __launch_bounds__(512) void k_win_attn(const bf16* __restrict__ q,
                                                  const bf16* __restrict__ ks,
                                                  const bf16* __restrict__ vt,
                                                  bf16* __restrict__ out)
{
    __shared__ bf16 Ks[2][32][136];
    __shared__ bf16 Vs[2][128][44];
    __shared__ bf16 Ps[8][16][44];

    const int t = threadIdx.x, lane = t & 63, wid = t >> 6;
    const int lr = lane & 15, lg = lane >> 4;
    const int wb = blockIdx.x;
    const int b  = wb >> 6, win = wb & 63;
    const int nh = win >> 3, nw = win & 7;
    const int qbase = blockIdx.y * 128 + wid * 16;

    const float SCALE   = 0.088388347648318447f;
    const float MASKRAW = 100.f / 0.088388347648318447f;

    auto tokOf = [&](int p) {
        int ph = nh * 12 + p / 40;
        int pw = nw * 40 + (p % 40);
        if (SHIFT) {
            ph += 6;  if (ph >= cH) ph -= cH;
            pw += 20; if (pw >= cW) pw -= cW;
        }
        return b * cNPIX + ph * cW + pw;
    };

    int qp = min(qbase + lr, 479);
    const bf16* qptr = q + (size_t)tokOf(qp) * 128;
    bf16x8 qf[4];
#pragma unroll
    for (int c = 0; c < 4; ++c)
        qf[c] = *(const bf16x8*)(qptr + c * 32 + lg * 8);

    int labq[4];
    if (SHIFT) {
#pragma unroll
        for (int r = 0; r < 4; ++r) {
            int qrow = min(qbase + lg * 4 + r, 479);
            int qr = qrow / 40, qc = qrow - qr * 40;
            int rh = (nh == 7) ? (qr < 6 ? 1 : 2) : 0;
            int rc = (nw == 7) ? (qc < 20 ? 1 : 2) : 0;
            labq[r] = rh * 3 + rc;
        }
    }

    const bf16* kbase = ks + (size_t)wb * 480 * 128;
    const bf16* vbase = vt + (size_t)wb * 128 * 480;
    auto loadK = [&](int kt) {
        return *(const bf16x8*)(kbase + (size_t)(kt * 32 + (t >> 4)) * 128 + (t & 15) * 8);
    };
    auto loadV = [&](int kt) {
        return *(const bf16x8*)(vbase + (size_t)(t >> 2) * 480 + kt * 32 + (t & 3) * 8);
    };

    bf16x8 kreg = loadK(0);
    bf16x8 vreg = loadV(0);
    *(bf16x8*)&Ks[0][t >> 4][(t & 15) * 8] = kreg;
    *(bf16x8*)&Vs[0][t >> 2][(t & 3) * 8]  = vreg;
    kreg = loadK(1);
    vreg = loadV(1);

    int kc0 = lr, kr0 = 0;
    int kc1 = 16 + lr, kr1 = 0;

    const f32x4 zero4 = {0.f, 0.f, 0.f, 0.f};
    float m_run[4] = {0.f, 0.f, 0.f, 0.f};
    float mguard = 8.f;
    f32x4 l4 = zero4;
    f32x4 o[8];
#pragma unroll
    for (int nf = 0; nf < 8; ++nf) o[nf] = zero4;

    bf16x8 ones8;
#pragma unroll
    for (int j = 0; j < 8; ++j) ones8[j] = (bf16)1.f;

    for (int kt = 0; kt < 15; ++kt) {
        const int cur = kt & 1;
        __syncthreads();
        if (kt + 1 < 15) {
            *(bf16x8*)&Ks[cur ^ 1][t >> 4][(t & 15) * 8] = kreg;
            *(bf16x8*)&Vs[cur ^ 1][t >> 2][(t & 3) * 8]  = vreg;
            if (kt + 2 < 15) {
                kreg = loadK(kt + 2);
                vreg = loadV(kt + 2);
            }
        }

        f32x4 s0 = zero4, s1 = zero4;
        __builtin_amdgcn_s_setprio(1);
#pragma unroll
        for (int c = 0; c < 4; ++c) {
            bf16x8 kf0 = *(const bf16x8*)&Ks[cur][lr][c * 32 + lg * 8];
            bf16x8 kf1 = *(const bf16x8*)&Ks[cur][16 + lr][c * 32 + lg * 8];
            s0 = MFMA_BF16(qf[c], kf0, s0);
            s1 = MFMA_BF16(qf[c], kf1, s1);
        }
        __builtin_amdgcn_s_setprio(0);

        if (SHIFT) {
            int rh0 = (nh == 7) ? (kr0 < 6 ? 1 : 2) : 0;
            int rc0 = (nw == 7) ? (kc0 < 20 ? 1 : 2) : 0;
            int rh1 = (nh == 7) ? (kr1 < 6 ? 1 : 2) : 0;
            int rc1 = (nw == 7) ? (kc1 < 20 ? 1 : 2) : 0;
            int lab0 = rh0 * 3 + rc0;
            int lab1 = rh1 * 3 + rc1;
#pragma unroll
            for (int r = 0; r < 4; ++r) {
                if (labq[r] != lab0) s0[r] -= MASKRAW;
                if (labq[r] != lab1) s1[r] -= MASKRAW;
            }
        }
        kc0 += 32; if (kc0 >= 40) { kc0 -= 40; ++kr0; }
        kc1 += 32; if (kc1 >= 40) { kc1 -= 40; ++kr1; }

        float tm = fmaxf(fmaxf(fmaxf(s0[0], s0[1]), fmaxf(s0[2], s0[3])),
                         fmaxf(fmaxf(s1[0], s1[1]), fmaxf(s1[2], s1[3])));
        if (__any(tm * SCALE > mguard)) {
#pragma unroll
            for (int r = 0; r < 4; ++r) {
                float mx = fmaxf(s0[r], s1[r]);
#pragma unroll
                for (int off = 1; off < 16; off <<= 1) mx = fmaxf(mx, __shfl_xor(mx, off));
                float nm = fmaxf(m_run[r], mx * SCALE);
                float sc = __expf(m_run[r] - nm);
#pragma unroll
                for (int nf = 0; nf < 8; ++nf) o[nf][r] *= sc;
                l4[r] *= sc;
                m_run[r] = nm;
            }
            mguard = fminf(fminf(m_run[0], m_run[1]), fminf(m_run[2], m_run[3])) + 8.f;
        }

#pragma unroll
        for (int r = 0; r < 4; ++r) {
            float p0 = __expf(fmaf(s0[r], SCALE, -m_run[r]));
            float p1 = __expf(fmaf(s1[r], SCALE, -m_run[r]));
            Ps[wid][lg * 4 + r][lr]      = (bf16)p0;
            Ps[wid][lg * 4 + r][16 + lr] = (bf16)p1;
        }

        bf16x8 pa = *(const bf16x8*)&Ps[wid][lr][lg * 8];
        __builtin_amdgcn_s_setprio(1);
        l4 = MFMA_BF16(pa, ones8, l4);
#pragma unroll
        for (int nf = 0; nf < 8; ++nf) {
            bf16x8 bv = *(const bf16x8*)&Vs[cur][nf * 16 + lr][lg * 8];
            o[nf] = MFMA_BF16(pa, bv, o[nf]);
        }
        __builtin_amdgcn_s_setprio(0);
    }

#pragma unroll
    for (int r = 0; r < 4; ++r) {
        int qrow = qbase + lg * 4 + r;
        if (qrow >= 480) continue;
        float inv = 1.f / (l4[r] + __expf(-m_run[r]));
        size_t ooff = (size_t)tokOf(qrow) * 128;
#pragma unroll
        for (int nf = 0; nf < 8; ++nf)
            out[ooff + nf * 16 + lr] = (bf16)(o[nf][r] * inv);
    }
}

// ---------------------------------------------------------------------------
// Host launcher
// ---------------------------------------------------------------------------
extern "C" void kernel_launch(void* const* d_in, const int* in_sizes, int n_in,
                              void* d_out, int out_size, void* d_ws, size_t ws_size,
                              hipStream_t stream)
{
    (void)in_sizes; (void)n_in; (void)out_size; (void)ws_size;

    const float* X = (const float*)d_in[0];

    char* ws = (char*)d_ws;
    bf16*  f    = (bf16*)ws;                                  ws += (size_t)cNTOK * 128 * 2;
    bf16*  xnb  = (bf16*)ws;                                  ws += (size_t)cNTOK * 128 * 2;
    bf16*  bufA = (bf16*)ws;                                  ws += (size_t)cNTOK * 512 * 2;
    bf16*  bufB = (bf16*)ws;                                  ws += (size_t)cNTOK * 512 * 2;
    bf16*  wts  = (bf16*)ws;

    size_t wo_off = 0;
    auto nextw = [&](int K, int M) { bf16* p = wts + wo_off; wo_off += (size_t)K * M; return p; };
    bf16* agg_w1t = nextw(256, 128);
    bf16* agg_w2t = nextw(128, 128);
    bf16* wolc    = nextw(256, 128);   // combined outlook: rows 0..127 wv, 128..208 wa, rest 0
    bf16* ol_wot  = nextw(128, 128);
    bf16* f1_w1t  = nextw(128, 512);
    bf16* f1_w2t  = nextw(512, 128);
    bf16* w_qkvt  = nextw(128, 384);
    bf16* w_wot   = nextw(128, 128);
    bf16* f2_w1t  = nextw(128, 512);
    bf16* f2_w2t  = nextw(512, 128);
    bf16* s_qkvt  = nextw(128, 384);
    bf16* s_wot   = nextw(128, 128);
    bf16* f3_w1t  = nextw(128, 512);
    bf16* f3_w2t  = nextw(512, 128);
    float* dwt1 = (float*)(wts + wo_off);
    float* dwt2 = dwt1 + 512 * 9;
    float* dwt3 = dwt2 + 512 * 9;
    float* ytab = dwt3 + 512 * 9;
    float* xtab = ytab + 96 * 64;
    float* bolc = xtab + 320 * 64;     // 256 floats combined bias

    // zero pad regions (graph-capture-safe async ops)
    hipMemsetAsync(wolc + 209 * 128, 0, (size_t)(256 - 209) * 128 * sizeof(bf16), stream);
    hipMemsetAsync(bolc, 0, 256 * sizeof(float), stream);
    hipMemcpyAsync(bolc + 128, d_in[9], 81 * sizeof(float), hipMemcpyDeviceToDevice, stream);

    WJobs jobs;
    int ji = 0;
    auto addj = [&](int src_idx, bf16* dst, int K, int M) {
        jobs.j[ji++] = WJob{(const float*)d_in[src_idx], dst, K, M};
    };
    addj(1,  agg_w1t, 256, 128);
    addj(3,  agg_w2t, 128, 128);
    addj(7,  wolc,            128, 128);   // ol_wv -> rows 0..127
    addj(8,  wolc + 128*128,  128, 81);    // ol_wa -> rows 128..208
    addj(10, ol_wot,  128, 128);
    addj(14, f1_w1t,  128, 512);
    addj(18, f1_w2t,  512, 128);
    addj(22, w_qkvt,           128, 128);
    addj(23, w_qkvt + 128*128, 128, 128);
    addj(24, w_qkvt + 256*128, 128, 128);
    addj(25, w_wot,   128, 128);
    addj(29, f2_w1t,  128, 512);
    addj(33, f2_w2t,  512, 128);
    addj(37, s_qkvt,           128, 128);
    addj(38, s_qkvt + 128*128, 128, 128);
    addj(39, s_qkvt + 256*128, 128, 128);
    addj(40, s_wot,   128, 128);
    addj(44, f3_w1t,  128, 512);
    addj(48, f3_w2t,  512, 128);
    k_wt<<<dim3(16, 16, 19), dim3(32, 8), 0, stream>>>(jobs);
    k_dwt<<<3, 256, 0, stream>>>((const float*)d_in[16], (const float*)d_in[31],
                                 (const float*)d_in[46], dwt1, dwt2, dwt3);
    k_postab<<<80, 256, 0, stream>>>(ytab, xtab);

    const int nTT = cNTOK / 128;   // 480 token tiles

    // ---- input transpose + aggregation MLP (agg_w2 epilogue emits ol-LN) ----
    k_chw2hwc<<<dim3(cNPIX / 32, 256 / 32, cB), dim3(32, 8), 0, stream>>>(X, bufA);
    k_gemm_res<true, true, false, false, false, false><<<nTT, 256, 0, stream>>>(
        bufA, agg_w1t, (const float*)d_in[2], nullptr, nullptr, bufB, nullptr, 256,
        nullptr, nullptr, nullptr, nullptr, nullptr);
    k_gemm_res<false, false, false, false, true, false><<<nTT, 256, 0, stream>>>(
        bufB, agg_w2t, (const float*)d_in[4], nullptr, f, nullptr, nullptr, 128,
        nullptr, nullptr, (const float*)d_in[5], (const float*)d_in[6], xnb);

    // ---- outlook attention: combined v+attn GEMM, gather, wo (emits f1-LN) ----
    {
        bf16* comb = bufA;                              // [tok][224]
        bf16* gout = bufB;                              // [tok][128]
        k_gemm128<2><<<nTT * 2, 256, 0, stream>>>(xnb, wolc, bolc, comb, 224, nullptr, nullptr);
        k_olk_gather<<<cNTOK / 16, 256, 0, stream>>>(comb, gout);
        k_gemm_res<false, false, true, false, true, false><<<nTT, 256, 0, stream>>>(
            gout, ol_wot, (const float*)d_in[11], f, f, nullptr, nullptr, 128,
            nullptr, nullptr, (const float*)d_in[12], (const float*)d_in[13], xnb);
    }

    // ---- conv FFN; w2 epilogue emits next block's LN (if lnG), or the
    //      transposed final output (f3) ----
    auto run_ffn = [&](int base, bf16* w1t, bf16* w2t, float* dwt, bool pos,
                       const float* lnG, const float* lnB, float* outT) {
        k_gemm128<-1><<<nTT * 4, 256, 0, stream>>>(
            xnb, w1t, (const float*)d_in[base + 3], bufA, 512, nullptr, nullptr);
        k_dwconv_gelu<<<cB * cH * 16, 256, 0, stream>>>(
            bufA, dwt, (const float*)d_in[base + 5], bufB);
        if (pos) {
            k_gemm_res<false, false, true, true, true, false><<<nTT, 256, 0, stream>>>(
                bufB, w2t, (const float*)d_in[base + 7], f, f, nullptr, nullptr, 512,
                ytab, xtab, lnG, lnB, xnb);
        } else if (lnG) {
            k_gemm_res<false, false, true, false, true, false><<<nTT, 256, 0, stream>>>(
                bufB, w2t, (const float*)d_in[base + 7], f, f, nullptr, nullptr, 512,
                nullptr, nullptr, lnG, lnB, xnb);
        } else {
            k_gemm_res<false, false, true, false, false, true><<<nTT, 256, 0, stream>>>(
                bufB, w2t, (const float*)d_in[base + 7], f, nullptr, nullptr, outT, 512,
                nullptr, nullptr, nullptr, nullptr, nullptr);
        }
    };

    // ---- window attention; wo epilogue emits next block's LN ----
    auto run_win = [&](int base, bf16* qkvt, bf16* wot, bool shift,
                       const float* lnG, const float* lnB) {
        bf16* qb  = bufA;
        bf16* ksb = bufA + (size_t)cNTOK * 128;
        bf16* vtb = bufA + (size_t)cNTOK * 256;
        bf16* ao  = bufB;
        if (shift)
            k_gemm128<1><<<nTT * 3, 256, 0, stream>>>(xnb, qkvt, nullptr, qb, 384, vtb, ksb);
        else
            k_gemm128<0><<<nTT * 3, 256, 0, stream>>>(xnb, qkvt, nullptr, qb, 384, vtb, ksb);
        if (shift) k_win_attn<true ><<<dim3(128, 4), 512, 0, stream>>>(qb, ksb, vtb, ao);
        else       k_win_attn<false><<<dim3(128, 4), 512, 0, stream>>>(qb, ksb, vtb, ao);
        k_gemm_res<false, false, true, false, true, false><<<nTT, 256, 0, stream>>>(
            ao, wot, (const float*)d_in[base + 6], f, f, nullptr, nullptr, 128,
            nullptr, nullptr, lnG, lnB, xnb);
    };

    run_ffn(12, f1_w1t, f1_w2t, dwt1, true,
            (const float*)d_in[20], (const float*)d_in[21], nullptr);   // f1
    run_win(20, w_qkvt, w_wot, false,
            (const float*)d_in[27], (const float*)d_in[28]);            // w
    run_ffn(27, f2_w1t, f2_w2t, dwt2, false,
            (const float*)d_in[35], (const float*)d_in[36], nullptr);   // f2
    run_win(35, s_qkvt, s_wot, true,
            (const float*)d_in[42], (const float*)d_in[43]);            // s
    run_ffn(42, f3_w1t, f3_w2t, dwt3, false, nullptr, nullptr,
            (float*)d_out);                                             // f3 -> d_out^T
}

// Round 20
// 515.272 us; speedup vs baseline: 1.0308x; 1.0308x over previous
//
#include <hip/hip_runtime.h>

typedef __bf16 bf16;
typedef __bf16 bf16x8 __attribute__((ext_vector_type(8)));
typedef __bf16 bf16x4 __attribute__((ext_vector_type(4)));
typedef float  f32x4  __attribute__((ext_vector_type(4)));

#define MFMA_BF16(a, b, c) __builtin_amdgcn_mfma_f32_16x16x32_bf16(a, b, c, 0, 0, 0)

constexpr int cB    = 2;
constexpr int cH    = 96;
constexpr int cW    = 320;
constexpr int cC    = 128;
constexpr int cNPIX = cH * cW;          // 30720
constexpr int cNTOK = cB * cNPIX;       // 61440
constexpr int cAS   = 84;               // padded attn-logit stride (81 -> 84)

// ---------------------------------------------------------------------------
// Weight transpose+convert: fp32 W (K x M) -> bf16 Wt (M x K)
// ---------------------------------------------------------------------------
struct WJob  { const float* src; bf16* dst; int K; int M; };
struct WJobs { WJob j[19]; };

__global__ __launch_bounds__(256) void k_wt(WJobs jobs)
{
    __shared__ float tile[32][33];
    const WJob jb = jobs.j[blockIdx.z];
    int k0 = blockIdx.y * 32, m0 = blockIdx.x * 32;
    if (k0 >= jb.K || m0 >= jb.M) return;
    int tx = threadIdx.x, ty = threadIdx.y;
#pragma unroll
    for (int i = 0; i < 32; i += 8) {
        int kk = k0 + ty + i, mm = m0 + tx;
        tile[ty + i][tx] = (kk < jb.K && mm < jb.M) ? jb.src[(size_t)kk * jb.M + mm] : 0.f;
    }
    __syncthreads();
#pragma unroll
    for (int i = 0; i < 32; i += 8) {
        int mm = m0 + ty + i, kk = k0 + tx;
        if (mm < jb.M && kk < jb.K)
            jb.dst[(size_t)mm * jb.K + kk] = (bf16)tile[tx][ty + i];
    }
}

__global__ __launch_bounds__(256) void k_dwt(const float* s0, const float* s1, const float* s2,
                                             float* d0, float* d1, float* d2)
{
    const float* s = blockIdx.x == 0 ? s0 : (blockIdx.x == 1 ? s1 : s2);
    float*       d = blockIdx.x == 0 ? d0 : (blockIdx.x == 1 ? d1 : d2);
    for (int i = threadIdx.x; i < 512 * 9; i += 256) {
        int c = i / 9, tap = i - c * 9;
        d[tap * 512 + c] = s[i];
    }
}

__global__ __launch_bounds__(256) void k_postab(float* __restrict__ yt, float* __restrict__ xt)
{
    int i = blockIdx.x * 256 + threadIdx.x;
    const float TWO_PI = 6.283185307179586f;
    const float KSC = -9.210340371976184f / 32.f;
    if (i < 96 * 64) {
        int h = i >> 6, c = i & 63;
        float p = (float)(h + 1) * (TWO_PI / (96.f + 1e-6f));
        float val = p * expf((float)(c >> 1) * KSC);
        yt[i] = (c & 1) ? cosf(val) : sinf(val);
    }
    if (i < 320 * 64) {
        int w = i >> 6, c = i & 63;
        float p = (float)(w + 1) * (TWO_PI / (320.f + 1e-6f));
        float val = p * expf((float)(c >> 1) * KSC);
        xt[i] = (c & 1) ? cosf(val) : sinf(val);
    }
}

// ---------------------------------------------------------------------------
// Input transpose (B, C=256, HW) -> (B, HW, C) bf16
// ---------------------------------------------------------------------------
__global__ __launch_bounds__(256) void k_chw2hwc(const float* __restrict__ in,
                                                 bf16* __restrict__ out)
{
    __shared__ float tile[32][33];
    const int Cc = 256;
    int s0 = blockIdx.x * 32;
    int c0 = blockIdx.y * 32;
    int b  = blockIdx.z;
    const float* ip = in  + (size_t)b * Cc * cNPIX;
    bf16*        op = out + (size_t)b * cNPIX * Cc;
    int tx = threadIdx.x, ty = threadIdx.y;
#pragma unroll
    for (int i = 0; i < 32; i += 8)
        tile[ty + i][tx] = ip[(size_t)(c0 + ty + i) * cNPIX + s0 + tx];
    __syncthreads();
#pragma unroll
    for (int i = 0; i < 32; i += 8)
        op[(size_t)(s0 + ty + i) * Cc + c0 + tx] = (bf16)tile[tx][ty + i];
}

// ---------------------------------------------------------------------------
// K=128 single-shot GEMM.
// ---------------------------------------------------------------------------
template<int QKVS>
__global__ __launch_bounds__(256) void k_gemm128(const bf16* __restrict__ A,
                                                 const bf16* __restrict__ Wt,
                                                 const float* __restrict__ bias,
                                                 bf16* __restrict__ outB, int M,
                                                 bf16* __restrict__ vtb,
                                                 bf16* __restrict__ ksb)
{
    __shared__ bf16 As[128][136];
    __shared__ bf16 Sb[64][136];

    const int NS = M >> 7;
    const int l  = blockIdx.x;
    const int r8 = l % (8 * NS);
    const int qq = l / (8 * NS);
    const int bm = (qq * 8 + (r8 & 7)) * 128;
    const int bn = (r8 >> 3) * 128;

    const int t = threadIdx.x;
    const int lane = t & 63, wid = t >> 6;
    const int wm = (wid >> 1) * 64, wn = (wid & 1) * 64;
    const int lr = lane & 15, lg = lane >> 4;

    const bf16* wp = Wt + (size_t)(bn + wn + lr) * 128 + lg * 8;
    bf16x8 bwA[4], bwB[4];
#pragma unroll
    for (int nf = 0; nf < 4; ++nf)
        bwA[nf] = *(const bf16x8*)(wp + (size_t)(nf * 16) * 128);

#pragma unroll
    for (int i = 0; i < 8; ++i) {
        int o = i * 256 + t;
        int row = o >> 4, cg = (o & 15) * 8;
        *(bf16x8*)&As[row][cg] = *(const bf16x8*)(A + (size_t)(bm + row) * 128 + cg);
    }
    __syncthreads();

    const f32x4 zero4 = {0.f, 0.f, 0.f, 0.f};
    f32x4 acc[4][4];
#pragma unroll
    for (int i = 0; i < 4; ++i)
#pragma unroll
        for (int j = 0; j < 4; ++j) acc[i][j] = zero4;

#pragma unroll
    for (int ks = 0; ks < 4; ++ks) {
        const bf16x8* cur = (ks & 1) ? bwB : bwA;
        bf16x8*       nxt = (ks & 1) ? bwA : bwB;
        if (ks < 3) {
#pragma unroll
            for (int nf = 0; nf < 4; ++nf)
                nxt[nf] = *(const bf16x8*)(wp + (size_t)(nf * 16) * 128 + (ks + 1) * 32);
        }
        bf16x8 af[4];
#pragma unroll
        for (int mf = 0; mf < 4; ++mf)
            af[mf] = *(const bf16x8*)&As[wm + mf*16 + lr][ks*32 + lg*8];
        __builtin_amdgcn_s_setprio(1);
#pragma unroll
        for (int mf = 0; mf < 4; ++mf)
#pragma unroll
            for (int nf = 0; nf < 4; ++nf)
                acc[mf][nf] = MFMA_BF16(af[mf], cur[nf], acc[mf][nf]);
        __builtin_amdgcn_s_setprio(0);
    }

    const bool vpart = (QKVS >= 0) && (bn == 256);
    const bool kpart = (QKVS >= 0) && (bn == 128);
    if (!vpart) {
#pragma unroll
        for (int half = 0; half < 2; ++half) {
            __syncthreads();
            if ((wid >> 1) == half) {
#pragma unroll
                for (int nf = 0; nf < 4; ++nf) {
                    int col = wn + nf * 16 + lr;
                    float bv = bias ? bias[bn + col] : 0.f;
#pragma unroll
                    for (int mf = 0; mf < 4; ++mf)
#pragma unroll
                        for (int r = 0; r < 4; ++r)
                            Sb[mf * 16 + lg * 4 + r][col] = (bf16)(acc[mf][nf][r] + bv);
                }
            }
            __syncthreads();
            if (!kpart) {
                const int ldo = (QKVS >= 0) ? 128 : M;
#pragma unroll
                for (int i = 0; i < 4; ++i) {
                    int o = i * 256 + t;
                    int row = o >> 4, cg = (o & 15) * 8;
                    *(bf16x8*)(outB + (size_t)(bm + half * 64 + row) * ldo + bn + cg) =
                        *(const bf16x8*)&Sb[row][cg];
                }
            } else {
#pragma unroll
                for (int i = 0; i < 4; ++i) {
                    int o = i * 256 + t;
                    int row = o >> 4, cg = (o & 15) * 8;
                    int gt = bm + half * 64 + row;
                    int b_ = gt / cNPIX, hw = gt - b_ * cNPIX;
                    int h = hw / cW, w = hw - (hw / cW) * cW;
                    int h0 = (QKVS == 1) ? ((h + 90) % 96)  : h;
                    int w0 = (QKVS == 1) ? ((w + 300) % 320) : w;
                    int nh = h0 / 12, kh = h0 - nh * 12;
                    int nw = w0 / 40, kw = w0 - nw * 40;
                    size_t krow = (size_t)((b_ * 64 + nh * 8 + nw) * 480 + kh * 40 + kw);
                    *(bf16x8*)(ksb + krow * 128 + cg) = *(const bf16x8*)&Sb[row][cg];
                }
            }
        }
    } else {
        const int lr_ = t & 15, cg_ = t >> 4;
        const int gt = bm + lr_ * 8;
        const int b_ = gt / cNPIX, hw = gt % cNPIX;
        const int h = hw / cW, w = hw % cW;
        const int h0 = (QKVS == 1) ? ((h + 90) % 96) : h;
        const int nh = h0 / 12, kh = h0 - nh * 12;
#pragma unroll
        for (int cp = 0; cp < 2; ++cp) {
            __syncthreads();
            if ((wid & 1) == cp) {
#pragma unroll
                for (int nf = 0; nf < 4; ++nf) {
                    int cl = nf * 16 + lr;
#pragma unroll
                    for (int mf = 0; mf < 4; ++mf)
#pragma unroll
                        for (int r = 0; r < 4; ++r)
                            Sb[cl][wm + mf * 16 + lg * 4 + r] = (bf16)acc[mf][nf][r];
                }
            }
            __syncthreads();
#pragma unroll
            for (int i = 0; i < 4; ++i) {
                int chl = cg_ + 16 * i;
                int ch  = cp * 64 + chl;
                bf16x8 e = *(const bf16x8*)&Sb[chl][lr_ * 8];
#pragma unroll
                for (int hi = 0; hi < 2; ++hi) {
                    int wv = (QKVS == 1) ? ((w + hi * 4 + 300) % 320) : (w + hi * 4);
                    int nw = wv / 40, kw = wv - nw * 40;
                    bf16* dst = vtb + ((size_t)((b_ * 64 + nh * 8 + nw) * 128 + ch)) * 480 + kh * 40 + kw;
                    bf16x4 hv;
#pragma unroll
                    for (int j = 0; j < 4; ++j) hv[j] = e[hi * 4 + j];
                    *(bf16x4*)dst = hv;
                }
            }
        }
    }
}

// ---------------------------------------------------------------------------
// K=128 GEMM for outlook attn logits: M=81 (stride 84), bf16 out.
// ---------------------------------------------------------------------------
__global__ __launch_bounds__(256) void k_gemm128_wa(const bf16* __restrict__ A,
                                                    const bf16* __restrict__ Wt,
                                                    const float* __restrict__ bias,
                                                    bf16* __restrict__ outA)
{
    __shared__ bf16 As[128][136];
    __shared__ bf16 Sb[64][88];

    const int bm = blockIdx.x * 128;
    const int t = threadIdx.x;
    const int lane = t & 63, wid = t >> 6;
    const int wm = (wid >> 1) * 64, wn = (wid & 1) * 64;
    const int lr = lane & 15, lg = lane >> 4;

    bf16x8 zrow;
#pragma unroll
    for (int j = 0; j < 8; ++j) zrow[j] = (bf16)0.f;

    bool okc[4];
    const bf16* wp = Wt + (size_t)(wn + lr) * 128 + lg * 8;
#pragma unroll
    for (int nf = 0; nf < 4; ++nf) okc[nf] = (wn + nf * 16 + lr) < 81;

    bf16x8 bwA[4], bwB[4];
#pragma unroll
    for (int nf = 0; nf < 4; ++nf)
        bwA[nf] = okc[nf] ? *(const bf16x8*)(wp + (size_t)(nf * 16) * 128) : zrow;

#pragma unroll
    for (int i = 0; i < 8; ++i) {
        int o = i * 256 + t;
        int row = o >> 4, cg = (o & 15) * 8;
        *(bf16x8*)&As[row][cg] = *(const bf16x8*)(A + (size_t)(bm + row) * 128 + cg);
    }
    __syncthreads();

    const f32x4 zero4 = {0.f, 0.f, 0.f, 0.f};
    f32x4 acc[4][4];
#pragma unroll
    for (int i = 0; i < 4; ++i)
#pragma unroll
        for (int j = 0; j < 4; ++j) acc[i][j] = zero4;

#pragma unroll
    for (int ks = 0; ks < 4; ++ks) {
        const bf16x8* cur = (ks & 1) ? bwB : bwA;
        bf16x8*       nxt = (ks & 1) ? bwA : bwB;
        if (ks < 3) {
#pragma unroll
            for (int nf = 0; nf < 4; ++nf)
                nxt[nf] = okc[nf] ? *(const bf16x8*)(wp + (size_t)(nf * 16) * 128 + (ks + 1) * 32) : zrow;
        }
        bf16x8 af[4];
#pragma unroll
        for (int mf = 0; mf < 4; ++mf)
            af[mf] = *(const bf16x8*)&As[wm + mf*16 + lr][ks*32 + lg*8];
        __builtin_amdgcn_s_setprio(1);
#pragma unroll
        for (int mf = 0; mf < 4; ++mf)
#pragma unroll
            for (int nf = 0; nf < 4; ++nf)
                acc[mf][nf] = MFMA_BF16(af[mf], cur[nf], acc[mf][nf]);
        __builtin_amdgcn_s_setprio(0);
    }

#pragma unroll
    for (int half = 0; half < 2; ++half) {
        __syncthreads();
        if ((wid >> 1) == half) {
#pragma unroll
            for (int nf = 0; nf < 4; ++nf) {
                int col = wn + nf * 16 + lr;
                if (col >= 84) continue;
                float bv = (col < 81) ? bias[col] : 0.f;
#pragma unroll
                for (int mf = 0; mf < 4; ++mf)
#pragma unroll
                    for (int r = 0; r < 4; ++r) {
                        float vv = (col < 81) ? (acc[mf][nf][r] + bv) : 0.f;
                        Sb[mf * 16 + lg * 4 + r][col] = (bf16)vv;
                    }
            }
        }
        __syncthreads();
#pragma unroll
        for (int i = 0; i < 6; ++i) {
            int o = i * 256 + t;
            if (o < 64 * 21) {
                int row = o / 21, cq = (o - row * 21) * 4;
                *(bf16x4*)(outA + (size_t)(bm + half * 64 + row) * cAS + cq) =
                    *(const bf16x4*)&Sb[row][cq];
            }
        }
    }
}

// ---------------------------------------------------------------------------
// Generic k-loop GEMM, M=128: 1-barrier dbuf K-loop, bf16 residual stream.
// ---------------------------------------------------------------------------
template<bool OUTBF, bool RELU, bool RES, bool POS, bool LNOUT, bool TOUT>
__global__ __launch_bounds__(256) void k_gemm_res(const bf16* __restrict__ A,
                                                  const bf16* __restrict__ Wt,
                                                  const float* __restrict__ bias,
                                                  const bf16* __restrict__ resB,
                                                  bf16* __restrict__ outFB,
                                                  bf16* __restrict__ outB,
                                                  float* __restrict__ outT,
                                                  int K,
                                                  const float* __restrict__ ytab,
                                                  const float* __restrict__ xtab,
                                                  const float* __restrict__ lng,
                                                  const float* __restrict__ lnb,
                                                  bf16* __restrict__ xnbO)
{
    __shared__ bf16 As[2][128][40];
    __shared__ bf16 Bs[2][128][40];
    __shared__ float Sf[64][136];

    const int bm = blockIdx.x * 128;
    const int t = threadIdx.x;
    const int lane = t & 63, wid = t >> 6;
    const int wm = (wid >> 1) * 64, wn = (wid & 1) * 64;
    const int lr = lane & 15, lg = lane >> 4;

    const int r0 = t >> 2,          kg0 = (t & 3) * 8;
    const int r1 = (t + 256) >> 2,  kg1 = ((t + 256) & 3) * 8;

    const int nks = K >> 5;

    auto loadAW = [&](int k0, bf16x8* ra, bf16x8* rw) {
        ra[0] = *(const bf16x8*)(A  + (size_t)(bm + r0) * K + k0 + kg0);
        ra[1] = *(const bf16x8*)(A  + (size_t)(bm + r1) * K + k0 + kg1);
        rw[0] = *(const bf16x8*)(Wt + (size_t)r0 * K + k0 + kg0);
        rw[1] = *(const bf16x8*)(Wt + (size_t)r1 * K + k0 + kg1);
    };

    bf16x8 ra[2], rw[2];
    loadAW(0, ra, rw);
    *(bf16x8*)&As[0][r0][kg0] = ra[0];
    *(bf16x8*)&As[0][r1][kg1] = ra[1];
    *(bf16x8*)&Bs[0][r0][kg0] = rw[0];
    *(bf16x8*)&Bs[0][r1][kg1] = rw[1];
    if (nks > 1) loadAW(32, ra, rw);

    const f32x4 zero4 = {0.f, 0.f, 0.f, 0.f};
    f32x4 acc[4][4];
#pragma unroll
    for (int i = 0; i < 4; ++i)
#pragma unroll
        for (int j = 0; j < 4; ++j) acc[i][j] = zero4;

    for (int ks = 0; ks < nks; ++ks) {
        const int cur = ks & 1;
        __syncthreads();
        if (ks + 1 < nks) {
            *(bf16x8*)&As[cur ^ 1][r0][kg0] = ra[0];
            *(bf16x8*)&As[cur ^ 1][r1][kg1] = ra[1];
            *(bf16x8*)&Bs[cur ^ 1][r0][kg0] = rw[0];
            *(bf16x8*)&Bs[cur ^ 1][r1][kg1] = rw[1];
            if (ks + 2 < nks) loadAW((ks + 2) * 32, ra, rw);
        }
        bf16x8 af[4], bf[4];
#pragma unroll
        for (int mf = 0; mf < 4; ++mf)
            af[mf] = *(const bf16x8*)&As[cur][wm + mf*16 + lr][lg * 8];
#pragma unroll
        for (int nf = 0; nf < 4; ++nf)
            bf[nf] = *(const bf16x8*)&Bs[cur][wn + nf*16 + lr][lg * 8];
        __builtin_amdgcn_s_setprio(1);
#pragma unroll
        for (int mf = 0; mf < 4; ++mf)
#pragma unroll
            for (int nf = 0; nf < 4; ++nf)
                acc[mf][nf] = MFMA_BF16(af[mf], bf[nf], acc[mf][nf]);
        __builtin_amdgcn_s_setprio(0);
    }
    __syncthreads();

    if (OUTBF) {
        bf16 (*Sb)[136] = (bf16(*)[136])Sf;
#pragma unroll
        for (int nf = 0; nf < 4; ++nf) {
            int col = wn + nf * 16 + lr;
            float bv = bias ? bias[col] : 0.f;
#pragma unroll
            for (int mf = 0; mf < 4; ++mf)
#pragma unroll
                for (int r = 0; r < 4; ++r) {
                    float vv = acc[mf][nf][r] + bv;
                    if (RELU) vv = fmaxf(vv, 0.f);
                    Sb[wm + mf * 16 + lg * 4 + r][col] = (bf16)vv;
                }
        }
        __syncthreads();
#pragma unroll
        for (int i = 0; i < 8; ++i) {
            int o = i * 256 + t;
            int row = o >> 4, cg = (o & 15) * 8;
            *(bf16x8*)(outB + (size_t)(bm + row) * 128 + cg) = *(const bf16x8*)&Sb[row][cg];
        }
    } else {
        const int b_   = bm / cNPIX;
        const int hw0  = bm - b_ * cNPIX;
        for (int half = 0; half < 2; ++half) {
            __syncthreads();
            if ((wid >> 1) == half) {
#pragma unroll
                for (int nf = 0; nf < 4; ++nf) {
                    int col = wn + nf * 16 + lr;
                    float bv = bias ? bias[col] : 0.f;
#pragma unroll
                    for (int mf = 0; mf < 4; ++mf)
#pragma unroll
                        for (int r = 0; r < 4; ++r)
                            Sf[mf * 16 + lg * 4 + r][col] = acc[mf][nf][r] + bv;
                }
            }
            __syncthreads();
            if (!TOUT) {
#pragma unroll
                for (int i = 0; i < 8; ++i) {
                    int o = i * 256 + t;
                    int row = o >> 5, cq = (o & 31) * 4;
                    int grow = bm + half * 64 + row;
                    float4 v = *(const float4*)&Sf[row][cq];
                    if (POS) {
                        int hw = grow % cNPIX;
                        int h = hw / cW, w = hw - (hw / cW) * cW;
                        float4 p = (cq < 64) ? *(const float4*)(ytab + (h << 6) + cq)
                                             : *(const float4*)(xtab + (w << 6) + cq - 64);
                        v.x += p.x; v.y += p.y; v.z += p.z; v.w += p.w;
                    }
                    if (RES) {
                        bf16x4 rr = *(const bf16x4*)(resB + (size_t)grow * 128 + cq);
                        v.x += (float)rr[0]; v.y += (float)rr[1];
                        v.z += (float)rr[2]; v.w += (float)rr[3];
                    }
                    if (LNOUT) {
                        float s  = v.x + v.y + v.z + v.w;
                        float sq = v.x*v.x + v.y*v.y + v.z*v.z + v.w*v.w;
#pragma unroll
                        for (int mk = 1; mk < 32; mk <<= 1) {
                            s  += __shfl_xor(s,  mk);
                            sq += __shfl_xor(sq, mk);
                        }
                        float mu = s * (1.f / 128.f);
                        float rs = rsqrtf(sq * (1.f / 128.f) - mu * mu + 1e-5f);
                        float4 g4 = *(const float4*)(lng + cq);
                        float4 b4 = *(const float4*)(lnb + cq);
                        bf16x4 xo;
                        xo[0] = (bf16)((v.x - mu) * rs * g4.x + b4.x);
                        xo[1] = (bf16)((v.y - mu) * rs * g4.y + b4.y);
                        xo[2] = (bf16)((v.z - mu) * rs * g4.z + b4.z);
                        xo[3] = (bf16)((v.w - mu) * rs * g4.w + b4.w);
                        *(bf16x4*)(xnbO + (size_t)grow * 128 + cq) = xo;
                    }
                    bf16x4 fv;
                    fv[0] = (bf16)v.x; fv[1] = (bf16)v.y;
                    fv[2] = (bf16)v.z; fv[3] = (bf16)v.w;
                    *(bf16x4*)(outFB + (size_t)grow * 128 + cq) = fv;
                }
            } else {
#pragma unroll
                for (int i = 0; i < 8; ++i) {
                    int o = i * 256 + t;
                    int row = o >> 5, cq = (o & 31) * 4;
                    int grow = bm + half * 64 + row;
                    float4 v = *(const float4*)&Sf[row][cq];
                    bf16x4 rr = *(const bf16x4*)(resB + (size_t)grow * 128 + cq);
                    v.x += (float)rr[0]; v.y += (float)rr[1];
                    v.z += (float)rr[2]; v.w += (float)rr[3];
                    *(float4*)&Sf[row][cq] = v;
                }
                __syncthreads();
                const int lane16 = t & 15;
#pragma unroll
                for (int p = 0; p < 8; ++p) {
                    int col = p * 16 + (t >> 4);
                    float4 v;
                    v.x = Sf[lane16 * 4 + 0][col];
                    v.y = Sf[lane16 * 4 + 1][col];
                    v.z = Sf[lane16 * 4 + 2][col];
                    v.w = Sf[lane16 * 4 + 3][col];
                    *(float4*)(outT + ((size_t)(b_ * 128 + col)) * cNPIX
                               + hw0 + half * 64 + lane16 * 4) = v;
                }
            }
        }
    }
}

// ---------------------------------------------------------------------------
// Outlook fused gather (R14 structure: LDS-staged neighborhood).
// ---------------------------------------------------------------------------
__global__ __launch_bounds__(256) void k_olk_gather(const bf16* __restrict__ v,
                                                    const bf16* __restrict__ attn,
                                                    bf16* __restrict__ y)
{
    __shared__ bf16  Ls[100][136];
    __shared__ float pr[16][84];
    __shared__ float coef[16][26];

    const int t  = threadIdx.x;
    const int px = t >> 4;
    const int j  = t & 15;
    const int pix0 = blockIdx.x * 16;
    const int b   = pix0 / cNPIX;
    const int hw0 = pix0 % cNPIX;
    const int h   = hw0 / cW, w0 = hw0 % cW;
    const int pix = pix0 + px;
    const int w   = w0 + px;

    const size_t bbase = (size_t)b * cNPIX;

    for (int e = px; e < 100; e += 16) {
        const int a  = e / 20, cc = e - a * 20;
        const int sh = h + a - 2, sw = w0 + cc - 2;
        bf16x8 val;
        if ((unsigned)sh < (unsigned)cH && (unsigned)sw < (unsigned)cW) {
            val = *(const bf16x8*)(v + (bbase + (size_t)sh * cW + sw) * 128 + j * 8);
        } else {
#pragma unroll
            for (int q = 0; q < 8; ++q) val[q] = (bf16)0.f;
        }
        *(bf16x8*)&Ls[e][j * 8] = val;
    }

    if (j < 9) {
        const int p  = j;
        const int pi = p / 3, pj = p - pi * 3;
        const int hh = h + 1 - pi, ww = w + 1 - pj;
        float prv[9];
        if ((unsigned)hh < (unsigned)cH && (unsigned)ww < (unsigned)cW) {
            const size_t row = (size_t)(bbase + (size_t)hh * cW + ww);
            const bf16* arow = attn + row * cAS + p * 9;
            float lg[9];
            float m = 0.f;
#pragma unroll
            for (int q = 0; q < 9; ++q) { lg[q] = (float)arow[q]; m = fmaxf(m, lg[q]); }
            float se = 0.f;
#pragma unroll
            for (int q = 0; q < 9; ++q) { prv[q] = __expf(lg[q] - m); se += prv[q]; }
            float inv = 1.f / (se + __expf(-m));
#pragma unroll
            for (int q = 0; q < 9; ++q) prv[q] *= inv;
        } else {
#pragma unroll
            for (int q = 0; q < 9; ++q) prv[q] = 0.f;
        }
#pragma unroll
        for (int q = 0; q < 9; ++q) pr[px][p * 9 + q] = prv[q];
    }
    __syncthreads();

    for (int d = j; d < 25; d += 16) {
        const int a  = d / 5, bb = d - a * 5;
        float s = 0.f;
#pragma unroll
        for (int pi = 0; pi < 3; ++pi) {
            const int qi = pi + a - 2;
            if ((unsigned)qi >= 3u) continue;
#pragma unroll
            for (int pj = 0; pj < 3; ++pj) {
                const int qj = pj + bb - 2;
                if ((unsigned)qj >= 3u) continue;
                s += pr[px][(pi * 3 + pj) * 9 + qi * 3 + qj];
            }
        }
        coef[px][d] = s;
    }
    __syncthreads();

    float acc[8] = {};
#pragma unroll
    for (int a = 0; a < 5; ++a) {
#pragma unroll
        for (int bb = 0; bb < 5; ++bb) {
            const float cf = coef[px][a * 5 + bb];
            const bf16x8 v8 = *(const bf16x8*)&Ls[a * 20 + px + bb][j * 8];
#pragma unroll
            for (int e = 0; e < 8; ++e) acc[e] = fmaf(cf, (float)v8[e], acc[e]);
        }
    }
    bf16x8 o8;
#pragma unroll
    for (int e = 0; e < 8; ++e) o8[e] = (bf16)acc[e];
    *(bf16x8*)(y + (size_t)pix * 128 + j * 8) = o8;
}

// ---------------------------------------------------------------------------
// Depthwise 3x3 + bias + fast GELU.
// ---------------------------------------------------------------------------
__global__ __launch_bounds__(256) void k_dwconv_gelu(const bf16* __restrict__ h1,
                                                     const float* __restrict__ dwt,
                                                     const float* __restrict__ bdw,
                                                     bf16* __restrict__ h2)
{
    const int t   = threadIdx.x;
    const int c2  = t * 2;
    const int blk = blockIdx.x;
    const int row = blk >> 4;
    const int seg = blk & 15;
    const int bb  = row / cH, h = row % cH;
    const int w0  = seg * 20;

    float2 wgt[9];
#pragma unroll
    for (int k = 0; k < 9; ++k)
        wgt[k] = *(const float2*)(dwt + k * 512 + c2);
    if (h == 0) {
        wgt[0].x = wgt[0].y = wgt[1].x = wgt[1].y = wgt[2].x = wgt[2].y = 0.f;
    }
    if (h == cH - 1) {
        wgt[6].x = wgt[6].y = wgt[7].x = wgt[7].y = wgt[8].x = wgt[8].y = 0.f;
    }
    const float2 bias = *(const float2*)(bdw + c2);

    const size_t base = (size_t)bb * cNPIX;
    const int hm = (h == 0) ? 0 : h - 1;
    const int hp = (h == cH - 1) ? h : h + 1;
    const bf16* rp0 = h1 + (base + (size_t)hm * cW + w0) * 512 + c2;
    const bf16* rp1 = h1 + (base + (size_t)h  * cW + w0) * 512 + c2;
    const bf16* rp2 = h1 + (base + (size_t)hp * cW + w0) * 512 + c2;

    auto ldc = [&](const bf16* rp, int wofs) -> float2 {
        unsigned u = *(const unsigned*)(rp + (size_t)wofs * 512);
        float2 r;
        r.x = __uint_as_float(u << 16);
        r.y = __uint_as_float(u & 0xffff0000u);
        return r;
    };
    auto gelu = [](float x) -> float {
        float x2 = x * x;
        float z2 = fmaf(x2 * x, 0.0713548162726f, 1.5957691216057308f * x);
        float t1 = 1.f / (1.f + __expf(-z2));
        return x * t1;
    };

    float2 cm[3], c0[3], cp[3];
    if (seg == 0) {
#pragma unroll
        for (int r = 0; r < 3; ++r) { cm[r].x = 0.f; cm[r].y = 0.f; }
    } else {
        cm[0] = ldc(rp0, -1); cm[1] = ldc(rp1, -1); cm[2] = ldc(rp2, -1);
    }
    c0[0] = ldc(rp0, 0); c0[1] = ldc(rp1, 0); c0[2] = ldc(rp2, 0);

    bf16* op = h2 + (base + (size_t)h * cW + w0) * 512 + c2;

    for (int j = 0; j < 20; ++j) {
        if (j == 19 && seg == 15) {
#pragma unroll
            for (int r = 0; r < 3; ++r) { cp[r].x = 0.f; cp[r].y = 0.f; }
        } else {
            cp[0] = ldc(rp0, j + 1); cp[1] = ldc(rp1, j + 1); cp[2] = ldc(rp2, j + 1);
        }
        float a0 = bias.x, a1 = bias.y;
#pragma unroll
        for (int r = 0; r < 3; ++r) {
            a0 = fmaf(cm[r].x, wgt[r * 3 + 0].x, a0);
            a1 = fmaf(cm[r].y, wgt[r * 3 + 0].y, a1);
            a0 = fmaf(c0[r].x, wgt[r * 3 + 1].x, a0);
            a1 = fmaf(c0[r].y, wgt[r * 3 + 1].y, a1);
            a0 = fmaf(cp[r].x, wgt[r * 3 + 2].x, a0);
            a1 = fmaf(cp[r].y, wgt[r * 3 + 2].y, a1);
        }
        a0 = gelu(a0);
        a1 = gelu(a1);
        union { bf16 hh[2]; unsigned int u; } o2;
        o2.hh[0] = (bf16)a0;
        o2.hh[1] = (bf16)a1;
        *(unsigned int*)(op + (size_t)j * 512) = o2.u;
#pragma unroll
        for (int r = 0; r < 3; ++r) { cm[r] = c0[r]; c0[r] = cp[r]; }
    }
}

// ---------------------------------------------------------------------------
// Window attention (8-wave, dbuf, 1 barrier/tile).
// ---------------------------------------------------------------------------
template<bool SHIFT>
__global__ __launch_bounds__(512) void k_win_attn(const bf16* __restrict__ q,
                                                  const bf16* __restrict__ ks,
                                                  const bf16* __restrict__ vt,
                                                  bf16* __restrict__ out)
{
    __shared__ bf16 Ks[2][32][136];
    __shared__ bf16 Vs[2][128][44];
    __shared__ bf16 Ps[8][16][44];

    const int t = threadIdx.x, lane = t & 63, wid = t >> 6;
    const int lr = lane & 15, lg = lane >> 4;
    const int wb = blockIdx.x;
    const int b  = wb >> 6, win = wb & 63;
    const int nh = win >> 3, nw = win & 7;
    const int qbase = blockIdx.y * 128 + wid * 16;

    const float SCALE   = 0.088388347648318447f;
    const float MASKRAW = 100.f / 0.088388347648318447f;

    auto tokOf = [&](int p) {
        int ph = nh * 12 + p / 40;
        int pw = nw * 40 + (p % 40);
        if (SHIFT) {
            ph += 6;  if (ph >= cH) ph -= cH;
            pw += 20; if (pw >= cW) pw -= cW;
        }
        return b * cNPIX + ph * cW + pw;
    };

    int qp = min(qbase + lr, 479);
    const bf16* qptr = q + (size_t)tokOf(qp) * 128;
    bf16x8 qf[4];
#pragma unroll
    for (int c = 0; c < 4; ++c)
        qf[c] = *(const bf16x8*)(qptr + c * 32 + lg * 8);

    int labq[4];
    if (SHIFT) {
#pragma unroll
        for (int r = 0; r < 4; ++r) {
            int qrow = min(qbase + lg * 4 + r, 479);
            int qr = qrow / 40, qc = qrow - qr * 40;
            int rh = (nh == 7) ? (qr < 6 ? 1 : 2) : 0;
            int rc = (nw == 7) ? (qc < 20 ? 1 : 2) : 0;
            labq[r] = rh * 3 + rc;
        }
    }

    const bf16* kbase = ks + (size_t)wb * 480 * 128;
    const bf16* vbase = vt + (size_t)wb * 128 * 480;
    auto loadK = [&](int kt) {
        return *(const bf16x8*)(kbase + (size_t)(kt * 32 + (t >> 4)) * 128 + (t & 15) * 8);
    };
    auto loadV = [&](int kt) {
        return *(const bf16x8*)(vbase + (size_t)(t >> 2) * 480 + kt * 32 + (t & 3) * 8);
    };

    bf16x8 kreg = loadK(0);
    bf16x8 vreg = loadV(0);
    *(bf16x8*)&Ks[0][t >> 4][(t & 15) * 8] = kreg;
    *(bf16x8*)&Vs[0][t >> 2][(t & 3) * 8]  = vreg;
    kreg = loadK(1);
    vreg = loadV(1);

    int kc0 = lr, kr0 = 0;
    int kc1 = 16 + lr, kr1 = 0;

    const f32x4 zero4 = {0.f, 0.f, 0.f, 0.f};
    float m_run[4] = {0.f, 0.f, 0.f, 0.f};
    float mguard = 8.f;
    f32x4 l4 = zero4;
    f32x4 o[8];
#pragma unroll
    for (int nf = 0; nf < 8; ++nf) o[nf] = zero4;

    bf16x8 ones8;
#pragma unroll
    for (int j = 0; j < 8; ++j) ones8[j] = (bf16)1.f;

    for (int kt = 0; kt < 15; ++kt) {
        const int cur = kt & 1;
        __syncthreads();
        if (kt + 1 < 15) {
            *(bf16x8*)&Ks[cur ^ 1][t >> 4][(t & 15) * 8] = kreg;
            *(bf16x8*)&Vs[cur ^ 1][t >> 2][(t & 3) * 8]  = vreg;
            if (kt + 2 < 15) {
                kreg = loadK(kt + 2);
                vreg = loadV(kt + 2);
            }
        }

        f32x4 s0 = zero4, s1 = zero4;
        __builtin_amdgcn_s_setprio(1);
#pragma unroll
        for (int c = 0; c < 4; ++c) {
            bf16x8 kf0 = *(const bf16x8*)&Ks[cur][lr][c * 32 + lg * 8];
            bf16x8 kf1 = *(const bf16x8*)&Ks[cur][16 + lr][c * 32 + lg * 8];
            s0 = MFMA_BF16(qf[c], kf0, s0);
            s1 = MFMA_BF16(qf[c], kf1, s1);
        }
        __builtin_amdgcn_s_setprio(0);

        if (SHIFT) {
            int rh0 = (nh == 7) ? (kr0 < 6 ? 1 : 2) : 0;
            int rc0 = (nw == 7) ? (kc0 < 20 ? 1 : 2) : 0;
            int rh1 = (nh == 7) ? (kr1 < 6 ? 1 : 2) : 0;
            int rc1 = (nw == 7) ? (kc1 < 20 ? 1 : 2) : 0;
            int lab0 = rh0 * 3 + rc0;
            int lab1 = rh1 * 3 + rc1;
#pragma unroll
            for (int r = 0; r < 4; ++r) {
                if (labq[r] != lab0) s0[r] -= MASKRAW;
                if (labq[r] != lab1) s1[r] -= MASKRAW;
            }
        }
        kc0 += 32; if (kc0 >= 40) { kc0 -= 40; ++kr0; }
        kc1 += 32; if (kc1 >= 40) { kc1 -= 40; ++kr1; }

        float tm = fmaxf(fmaxf(fmaxf(s0[0], s0[1]), fmaxf(s0[2], s0[3])),
                         fmaxf(fmaxf(s1[0], s1[1]), fmaxf(s1[2], s1[3])));
        if (__any(tm * SCALE > mguard)) {
#pragma unroll
            for (int r = 0; r < 4; ++r) {
                float mx = fmaxf(s0[r], s1[r]);
#pragma unroll
                for (int off = 1; off < 16; off <<= 1) mx = fmaxf(mx, __shfl_xor(mx, off));
                float nm = fmaxf(m_run[r], mx * SCALE);
                float sc = __expf(m_run[r] - nm);
#pragma unroll
                for (int nf = 0; nf < 8; ++nf) o[nf][r] *= sc;
                l4[r] *= sc;
                m_run[r] = nm;
            }
            mguard = fminf(fminf(m_run[0], m_run[1]), fminf(m_run[2], m_run[3])) + 8.f;
        }

#pragma unroll
        for (int r = 0; r < 4; ++r) {
            float p0 = __expf(fmaf(s0[r], SCALE, -m_run[r]));
            float p1 = __expf(fmaf(s1[r], SCALE, -m_run[r]));
            Ps[wid][lg * 4 + r][lr]      = (bf16)p0;
            Ps[wid][lg * 4 + r][16 + lr] = (bf16)p1;
        }

        bf16x8 pa = *(const bf16x8*)&Ps[wid][lr][lg * 8];
        __builtin_amdgcn_s_setprio(1);
        l4 = MFMA_BF16(pa, ones8, l4);
#pragma unroll
        for (int nf = 0; nf < 8; ++nf) {
            bf16x8 bv = *(const bf16x8*)&Vs[cur][nf * 16 + lr][lg * 8];
            o[nf] = MFMA_BF16(pa, bv, o[nf]);
        }
        __builtin_amdgcn_s_setprio(0);
    }

#pragma unroll
    for (int r = 0; r < 4; ++r) {
        int qrow = qbase + lg * 4 + r;
        if (qrow >= 480) continue;
        float inv = 1.f / (l4[r] + __expf(-m_run[r]));
        size_t ooff = (size_t)tokOf(qrow) * 128;
#pragma unroll
        for (int nf = 0; nf < 8; ++nf)
            out[ooff + nf * 16 + lr] = (bf16)(o[nf][r] * inv);
    }
}

// ---------------------------------------------------------------------------
// Host launcher
// ---------------------------------------------------------------------------
extern "C" void kernel_launch(void* const* d_in, const int* in_sizes, int n_in,
                              void* d_out, int out_size, void* d_ws, size_t ws_size,
                              hipStream_t stream)
{
    (void)in_sizes; (void)n_in; (void)out_size; (void)ws_size;

    const float* X = (const float*)d_in[0];

    char* ws = (char*)d_ws;
    bf16*  f    = (bf16*)ws;                                  ws += (size_t)cNTOK * 128 * 2;
    bf16*  xnb  = (bf16*)ws;                                  ws += (size_t)cNTOK * 128 * 2;
    bf16*  bufA = (bf16*)ws;                                  ws += (size_t)cNTOK * 512 * 2;
    bf16*  bufB = (bf16*)ws;                                  ws += (size_t)cNTOK * 512 * 2;
    bf16*  wts  = (bf16*)ws;

    size_t wo_off = 0;
    auto nextw = [&](int K, int M) { bf16* p = wts + wo_off; wo_off += (size_t)K * M; return p; };
    bf16* agg_w1t = nextw(256, 128);
    bf16* agg_w2t = nextw(128, 128);
    bf16* ol_wvt  = nextw(128, 128);
    bf16* ol_wat  = nextw(128, 81);
    bf16* ol_wot  = nextw(128, 128);
    bf16* f1_w1t  = nextw(128, 512);
    bf16* f1_w2t  = nextw(512, 128);
    bf16* w_qkvt  = nextw(128, 384);
    bf16* w_wot   = nextw(128, 128);
    bf16* f2_w1t  = nextw(128, 512);
    bf16* f2_w2t  = nextw(512, 128);
    bf16* s_qkvt  = nextw(128, 384);
    bf16* s_wot   = nextw(128, 128);
    bf16* f3_w1t  = nextw(128, 512);
    bf16* f3_w2t  = nextw(512, 128);
    float* dwt1 = (float*)(wts + wo_off);
    float* dwt2 = dwt1 + 512 * 9;
    float* dwt3 = dwt2 + 512 * 9;
    float* ytab = dwt3 + 512 * 9;
    float* xtab = ytab + 96 * 64;

    WJobs jobs;
    int ji = 0;
    auto addj = [&](int src_idx, bf16* dst, int K, int M) {
        jobs.j[ji++] = WJob{(const float*)d_in[src_idx], dst, K, M};
    };
    addj(1,  agg_w1t, 256, 128);
    addj(3,  agg_w2t, 128, 128);
    addj(7,  ol_wvt,  128, 128);
    addj(8,  ol_wat,  128, 81);
    addj(10, ol_wot,  128, 128);
    addj(14, f1_w1t,  128, 512);
    addj(18, f1_w2t,  512, 128);
    addj(22, w_qkvt,           128, 128);
    addj(23, w_qkvt + 128*128, 128, 128);
    addj(24, w_qkvt + 256*128, 128, 128);
    addj(25, w_wot,   128, 128);
    addj(29, f2_w1t,  128, 512);
    addj(33, f2_w2t,  512, 128);
    addj(37, s_qkvt,           128, 128);
    addj(38, s_qkvt + 128*128, 128, 128);
    addj(39, s_qkvt + 256*128, 128, 128);
    addj(40, s_wot,   128, 128);
    addj(44, f3_w1t,  128, 512);
    addj(48, f3_w2t,  512, 128);
    k_wt<<<dim3(16, 16, 19), dim3(32, 8), 0, stream>>>(jobs);
    k_dwt<<<3, 256, 0, stream>>>((const float*)d_in[16], (const float*)d_in[31],
                                 (const float*)d_in[46], dwt1, dwt2, dwt3);
    k_postab<<<80, 256, 0, stream>>>(ytab, xtab);

    const int nTT = cNTOK / 128;   // 480 token tiles

    // ---- input transpose + aggregation MLP (agg_w2 epilogue emits ol-LN) ----
    k_chw2hwc<<<dim3(cNPIX / 32, 256 / 32, cB), dim3(32, 8), 0, stream>>>(X, bufA);
    k_gemm_res<true, true, false, false, false, false><<<nTT, 256, 0, stream>>>(
        bufA, agg_w1t, (const float*)d_in[2], nullptr, nullptr, bufB, nullptr, 256,
        nullptr, nullptr, nullptr, nullptr, nullptr);
    k_gemm_res<false, false, false, false, true, false><<<nTT, 256, 0, stream>>>(
        bufB, agg_w2t, (const float*)d_in[4], nullptr, f, nullptr, nullptr, 128,
        nullptr, nullptr, (const float*)d_in[5], (const float*)d_in[6], xnb);

    // ---- outlook attention (ol_wo epilogue emits f1-LN) ----
    {
        bf16*  vb   = bufA;
        bf16*  gout = bufA + (size_t)cNTOK * 128;
        bf16*  atn  = bufB;
        k_gemm128<-1><<<nTT, 256, 0, stream>>>(xnb, ol_wvt, nullptr, vb, 128, nullptr, nullptr);
        k_gemm128_wa<<<nTT, 256, 0, stream>>>(xnb, ol_wat, (const float*)d_in[9], atn);
        k_olk_gather<<<cNTOK / 16, 256, 0, stream>>>(vb, atn, gout);
        k_gemm_res<false, false, true, false, true, false><<<nTT, 256, 0, stream>>>(
            gout, ol_wot, (const float*)d_in[11], f, f, nullptr, nullptr, 128,
            nullptr, nullptr, (const float*)d_in[12], (const float*)d_in[13], xnb);
    }

    // ---- conv FFN; w2 epilogue emits next block's LN (if lnG), or the
    //      transposed final output (f3) ----
    auto run_ffn = [&](int base, bf16* w1t, bf16* w2t, float* dwt, bool pos,
                       const float* lnG, const float* lnB, float* outT) {
        k_gemm128<-1><<<nTT * 4, 256, 0, stream>>>(
            xnb, w1t, (const float*)d_in[base + 3], bufA, 512, nullptr, nullptr);
        k_dwconv_gelu<<<cB * cH * 16, 256, 0, stream>>>(
            bufA, dwt, (const float*)d_in[base + 5], bufB);
        if (pos) {
            k_gemm_res<false, false, true, true, true, false><<<nTT, 256, 0, stream>>>(
                bufB, w2t, (const float*)d_in[base + 7], f, f, nullptr, nullptr, 512,
                ytab, xtab, lnG, lnB, xnb);
        } else if (lnG) {
            k_gemm_res<false, false, true, false, true, false><<<nTT, 256, 0, stream>>>(
                bufB, w2t, (const float*)d_in[base + 7], f, f, nullptr, nullptr, 512,
                nullptr, nullptr, lnG, lnB, xnb);
        } else {
            k_gemm_res<false, false, true, false, false, true><<<nTT, 256, 0, stream>>>(
                bufB, w2t, (const float*)d_in[base + 7], f, nullptr, nullptr, outT, 512,
                nullptr, nullptr, nullptr, nullptr, nullptr);
        }
    };

    // ---- window attention; wo epilogue emits next block's LN ----
    auto run_win = [&](int base, bf16* qkvt, bf16* wot, bool shift,
                       const float* lnG, const float* lnB) {
        bf16* qb  = bufA;
        bf16* ksb = bufA + (size_t)cNTOK * 128;
        bf16* vtb = bufA + (size_t)cNTOK * 256;
        bf16* ao  = bufB;
        if (shift)
            k_gemm128<1><<<nTT * 3, 256, 0, stream>>>(xnb, qkvt, nullptr, qb, 384, vtb, ksb);
        else
            k_gemm128<0><<<nTT * 3, 256, 0, stream>>>(xnb, qkvt, nullptr, qb, 384, vtb, ksb);
        if (shift) k_win_attn<true ><<<dim3(128, 4), 512, 0, stream>>>(qb, ksb, vtb, ao);
        else       k_win_attn<false><<<dim3(128, 4), 512, 0, stream>>>(qb, ksb, vtb, ao);
        k_gemm_res<false, false, true, false, true, false><<<nTT, 256, 0, stream>>>(
            ao, wot, (const float*)d_in[base + 6], f, f, nullptr, nullptr, 128,
            nullptr, nullptr, lnG, lnB, xnb);
    };

    run_ffn(12, f1_w1t, f1_w2t, dwt1, true,
            (const float*)d_in[20], (const float*)d_in[21], nullptr);   // f1
    run_win(20, w_qkvt, w_wot, false,
            (const float*)d_in[27], (const float*)d_in[28]);            // w
    run_ffn(27, f2_w1t, f2_w2t, dwt2, false,
            (const float*)d_in[35], (const float*)d_in[36], nullptr);   // f2
    run_win(35, s_qkvt, s_wot, true,
            (const float*)d_in[42], (const float*)d_in[43]);            // s
    run_ffn(42, f3_w1t, f3_w2t, dwt3, false, nullptr, nullptr,
            (float*)d_out);                                             // f3 -> d_out^T
}

// Round 21
// 512.727 us; speedup vs baseline: 1.0359x; 1.0050x over previous
//
#include <hip/hip_runtime.h>

typedef __bf16 bf16;
typedef __bf16 bf16x8 __attribute__((ext_vector_type(8)));
typedef __bf16 bf16x4 __attribute__((ext_vector_type(4)));
typedef float  f32x4  __attribute__((ext_vector_type(4)));

#define MFMA_BF16(a, b, c) __builtin_amdgcn_mfma_f32_16x16x32_bf16(a, b, c, 0, 0, 0)

constexpr int cB    = 2;
constexpr int cH    = 96;
constexpr int cW    = 320;
constexpr int cC    = 128;
constexpr int cNPIX = cH * cW;          // 30720
constexpr int cNTOK = cB * cNPIX;       // 61440
constexpr int cAS   = 84;               // padded attn-logit stride (81 -> 84)

// ---------------------------------------------------------------------------
// Weight transpose+convert: fp32 W (K x M) -> bf16 Wt (M x K)
// ---------------------------------------------------------------------------
struct WJob  { const float* src; bf16* dst; int K; int M; };
struct WJobs { WJob j[19]; };

__global__ __launch_bounds__(256) void k_wt(WJobs jobs)
{
    __shared__ float tile[32][33];
    const WJob jb = jobs.j[blockIdx.z];
    int k0 = blockIdx.y * 32, m0 = blockIdx.x * 32;
    if (k0 >= jb.K || m0 >= jb.M) return;
    int tx = threadIdx.x, ty = threadIdx.y;
#pragma unroll
    for (int i = 0; i < 32; i += 8) {
        int kk = k0 + ty + i, mm = m0 + tx;
        tile[ty + i][tx] = (kk < jb.K && mm < jb.M) ? jb.src[(size_t)kk * jb.M + mm] : 0.f;
    }
    __syncthreads();
#pragma unroll
    for (int i = 0; i < 32; i += 8) {
        int mm = m0 + ty + i, kk = k0 + tx;
        if (mm < jb.M && kk < jb.K)
            jb.dst[(size_t)mm * jb.K + kk] = (bf16)tile[tx][ty + i];
    }
}

__global__ __launch_bounds__(256) void k_dwt(const float* s0, const float* s1, const float* s2,
                                             float* d0, float* d1, float* d2)
{
    const float* s = blockIdx.x == 0 ? s0 : (blockIdx.x == 1 ? s1 : s2);
    float*       d = blockIdx.x == 0 ? d0 : (blockIdx.x == 1 ? d1 : d2);
    for (int i = threadIdx.x; i < 512 * 9; i += 256) {
        int c = i / 9, tap = i - c * 9;
        d[tap * 512 + c] = s[i];
    }
}

__global__ __launch_bounds__(256) void k_postab(float* __restrict__ yt, float* __restrict__ xt)
{
    int i = blockIdx.x * 256 + threadIdx.x;
    const float TWO_PI = 6.283185307179586f;
    const float KSC = -9.210340371976184f / 32.f;
    if (i < 96 * 64) {
        int h = i >> 6, c = i & 63;
        float p = (float)(h + 1) * (TWO_PI / (96.f + 1e-6f));
        float val = p * expf((float)(c >> 1) * KSC);
        yt[i] = (c & 1) ? cosf(val) : sinf(val);
    }
    if (i < 320 * 64) {
        int w = i >> 6, c = i & 63;
        float p = (float)(w + 1) * (TWO_PI / (320.f + 1e-6f));
        float val = p * expf((float)(c >> 1) * KSC);
        xt[i] = (c & 1) ? cosf(val) : sinf(val);
    }
}

// ---------------------------------------------------------------------------
// Input transpose (B, C=256, HW) -> (B, HW, C) bf16
// ---------------------------------------------------------------------------
__global__ __launch_bounds__(256) void k_chw2hwc(const float* __restrict__ in,
                                                 bf16* __restrict__ out)
{
    __shared__ float tile[32][33];
    const int Cc = 256;
    int s0 = blockIdx.x * 32;
    int c0 = blockIdx.y * 32;
    int b  = blockIdx.z;
    const float* ip = in  + (size_t)b * Cc * cNPIX;
    bf16*        op = out + (size_t)b * cNPIX * Cc;
    int tx = threadIdx.x, ty = threadIdx.y;
#pragma unroll
    for (int i = 0; i < 32; i += 8)
        tile[ty + i][tx] = ip[(size_t)(c0 + ty + i) * cNPIX + s0 + tx];
    __syncthreads();
#pragma unroll
    for (int i = 0; i < 32; i += 8)
        op[(size_t)(s0 + ty + i) * Cc + c0 + tx] = (bf16)tile[tx][ty + i];
}

// ---------------------------------------------------------------------------
// K=128 single-shot GEMM. LDS: Sb overlays As (barrier-separated lifetimes)
// -> 34.8 KB, 4 blocks/CU.
// ---------------------------------------------------------------------------
template<int QKVS>
__global__ __launch_bounds__(256) void k_gemm128(const bf16* __restrict__ A,
                                                 const bf16* __restrict__ Wt,
                                                 const float* __restrict__ bias,
                                                 bf16* __restrict__ outB, int M,
                                                 bf16* __restrict__ vtb,
                                                 bf16* __restrict__ ksb)
{
    __shared__ __attribute__((aligned(16))) char smem[128 * 136 * sizeof(bf16)];
    bf16 (*As)[136] = (bf16(*)[136])smem;   // live: staging + k-loop
    bf16 (*Sb)[136] = (bf16(*)[136])smem;   // live: epilogue (post-barrier)

    const int NS = M >> 7;
    const int l  = blockIdx.x;
    const int r8 = l % (8 * NS);
    const int qq = l / (8 * NS);
    const int bm = (qq * 8 + (r8 & 7)) * 128;
    const int bn = (r8 >> 3) * 128;

    const int t = threadIdx.x;
    const int lane = t & 63, wid = t >> 6;
    const int wm = (wid >> 1) * 64, wn = (wid & 1) * 64;
    const int lr = lane & 15, lg = lane >> 4;

    const bf16* wp = Wt + (size_t)(bn + wn + lr) * 128 + lg * 8;
    bf16x8 bwA[4], bwB[4];
#pragma unroll
    for (int nf = 0; nf < 4; ++nf)
        bwA[nf] = *(const bf16x8*)(wp + (size_t)(nf * 16) * 128);

#pragma unroll
    for (int i = 0; i < 8; ++i) {
        int o = i * 256 + t;
        int row = o >> 4, cg = (o & 15) * 8;
        *(bf16x8*)&As[row][cg] = *(const bf16x8*)(A + (size_t)(bm + row) * 128 + cg);
    }
    __syncthreads();

    const f32x4 zero4 = {0.f, 0.f, 0.f, 0.f};
    f32x4 acc[4][4];
#pragma unroll
    for (int i = 0; i < 4; ++i)
#pragma unroll
        for (int j = 0; j < 4; ++j) acc[i][j] = zero4;

#pragma unroll
    for (int ks = 0; ks < 4; ++ks) {
        const bf16x8* cur = (ks & 1) ? bwB : bwA;
        bf16x8*       nxt = (ks & 1) ? bwA : bwB;
        if (ks < 3) {
#pragma unroll
            for (int nf = 0; nf < 4; ++nf)
                nxt[nf] = *(const bf16x8*)(wp + (size_t)(nf * 16) * 128 + (ks + 1) * 32);
        }
        bf16x8 af[4];
#pragma unroll
        for (int mf = 0; mf < 4; ++mf)
            af[mf] = *(const bf16x8*)&As[wm + mf*16 + lr][ks*32 + lg*8];
        __builtin_amdgcn_s_setprio(1);
#pragma unroll
        for (int mf = 0; mf < 4; ++mf)
#pragma unroll
            for (int nf = 0; nf < 4; ++nf)
                acc[mf][nf] = MFMA_BF16(af[mf], cur[nf], acc[mf][nf]);
        __builtin_amdgcn_s_setprio(0);
    }

    const bool vpart = (QKVS >= 0) && (bn == 256);
    const bool kpart = (QKVS >= 0) && (bn == 128);
    if (!vpart) {
#pragma unroll
        for (int half = 0; half < 2; ++half) {
            __syncthreads();
            if ((wid >> 1) == half) {
#pragma unroll
                for (int nf = 0; nf < 4; ++nf) {
                    int col = wn + nf * 16 + lr;
                    float bv = bias ? bias[bn + col] : 0.f;
#pragma unroll
                    for (int mf = 0; mf < 4; ++mf)
#pragma unroll
                        for (int r = 0; r < 4; ++r)
                            Sb[mf * 16 + lg * 4 + r][col] = (bf16)(acc[mf][nf][r] + bv);
                }
            }
            __syncthreads();
            if (!kpart) {
                const int ldo = (QKVS >= 0) ? 128 : M;
#pragma unroll
                for (int i = 0; i < 4; ++i) {
                    int o = i * 256 + t;
                    int row = o >> 4, cg = (o & 15) * 8;
                    *(bf16x8*)(outB + (size_t)(bm + half * 64 + row) * ldo + bn + cg) =
                        *(const bf16x8*)&Sb[row][cg];
                }
            } else {
#pragma unroll
                for (int i = 0; i < 4; ++i) {
                    int o = i * 256 + t;
                    int row = o >> 4, cg = (o & 15) * 8;
                    int gt = bm + half * 64 + row;
                    int b_ = gt / cNPIX, hw = gt - b_ * cNPIX;
                    int h = hw / cW, w = hw - (hw / cW) * cW;
                    int h0 = (QKVS == 1) ? ((h + 90) % 96)  : h;
                    int w0 = (QKVS == 1) ? ((w + 300) % 320) : w;
                    int nh = h0 / 12, kh = h0 - nh * 12;
                    int nw = w0 / 40, kw = w0 - nw * 40;
                    size_t krow = (size_t)((b_ * 64 + nh * 8 + nw) * 480 + kh * 40 + kw);
                    *(bf16x8*)(ksb + krow * 128 + cg) = *(const bf16x8*)&Sb[row][cg];
                }
            }
        }
    } else {
        const int lr_ = t & 15, cg_ = t >> 4;
        const int gt = bm + lr_ * 8;
        const int b_ = gt / cNPIX, hw = gt % cNPIX;
        const int h = hw / cW, w = hw % cW;
        const int h0 = (QKVS == 1) ? ((h + 90) % 96) : h;
        const int nh = h0 / 12, kh = h0 - nh * 12;
#pragma unroll
        for (int cp = 0; cp < 2; ++cp) {
            __syncthreads();
            if ((wid & 1) == cp) {
#pragma unroll
                for (int nf = 0; nf < 4; ++nf) {
                    int cl = nf * 16 + lr;
#pragma unroll
                    for (int mf = 0; mf < 4; ++mf)
#pragma unroll
                        for (int r = 0; r < 4; ++r)
                            Sb[cl][wm + mf * 16 + lg * 4 + r] = (bf16)acc[mf][nf][r];
                }
            }
            __syncthreads();
#pragma unroll
            for (int i = 0; i < 4; ++i) {
                int chl = cg_ + 16 * i;
                int ch  = cp * 64 + chl;
                bf16x8 e = *(const bf16x8*)&Sb[chl][lr_ * 8];
#pragma unroll
                for (int hi = 0; hi < 2; ++hi) {
                    int wv = (QKVS == 1) ? ((w + hi * 4 + 300) % 320) : (w + hi * 4);
                    int nw = wv / 40, kw = wv - nw * 40;
                    bf16* dst = vtb + ((size_t)((b_ * 64 + nh * 8 + nw) * 128 + ch)) * 480 + kh * 40 + kw;
                    bf16x4 hv;
#pragma unroll
                    for (int j = 0; j < 4; ++j) hv[j] = e[hi * 4 + j];
                    *(bf16x4*)dst = hv;
                }
            }
        }
    }
}

// ---------------------------------------------------------------------------
// K=128 GEMM for outlook attn logits: M=81 (stride 84). Sb overlays As.
// ---------------------------------------------------------------------------
__global__ __launch_bounds__(256) void k_gemm128_wa(const bf16* __restrict__ A,
                                                    const bf16* __restrict__ Wt,
                                                    const float* __restrict__ bias,
                                                    bf16* __restrict__ outA)
{
    __shared__ __attribute__((aligned(16))) char smem[128 * 136 * sizeof(bf16)];
    bf16 (*As)[136] = (bf16(*)[136])smem;
    bf16 (*Sb)[88]  = (bf16(*)[88])smem;

    const int bm = blockIdx.x * 128;
    const int t = threadIdx.x;
    const int lane = t & 63, wid = t >> 6;
    const int wm = (wid >> 1) * 64, wn = (wid & 1) * 64;
    const int lr = lane & 15, lg = lane >> 4;

    bf16x8 zrow;
#pragma unroll
    for (int j = 0; j < 8; ++j) zrow[j] = (bf16)0.f;

    bool okc[4];
    const bf16* wp = Wt + (size_t)(wn + lr) * 128 + lg * 8;
#pragma unroll
    for (int nf = 0; nf < 4; ++nf) okc[nf] = (wn + nf * 16 + lr) < 81;

    bf16x8 bwA[4], bwB[4];
#pragma unroll
    for (int nf = 0; nf < 4; ++nf)
        bwA[nf] = okc[nf] ? *(const bf16x8*)(wp + (size_t)(nf * 16) * 128) : zrow;

#pragma unroll
    for (int i = 0; i < 8; ++i) {
        int o = i * 256 + t;
        int row = o >> 4, cg = (o & 15) * 8;
        *(bf16x8*)&As[row][cg] = *(const bf16x8*)(A + (size_t)(bm + row) * 128 + cg);
    }
    __syncthreads();

    const f32x4 zero4 = {0.f, 0.f, 0.f, 0.f};
    f32x4 acc[4][4];
#pragma unroll
    for (int i = 0; i < 4; ++i)
#pragma unroll
        for (int j = 0; j < 4; ++j) acc[i][j] = zero4;

#pragma unroll
    for (int ks = 0; ks < 4; ++ks) {
        const bf16x8* cur = (ks & 1) ? bwB : bwA;
        bf16x8*       nxt = (ks & 1) ? bwA : bwB;
        if (ks < 3) {
#pragma unroll
            for (int nf = 0; nf < 4; ++nf)
                nxt[nf] = okc[nf] ? *(const bf16x8*)(wp + (size_t)(nf * 16) * 128 + (ks + 1) * 32) : zrow;
        }
        bf16x8 af[4];
#pragma unroll
        for (int mf = 0; mf < 4; ++mf)
            af[mf] = *(const bf16x8*)&As[wm + mf*16 + lr][ks*32 + lg*8];
        __builtin_amdgcn_s_setprio(1);
#pragma unroll
        for (int mf = 0; mf < 4; ++mf)
#pragma unroll
            for (int nf = 0; nf < 4; ++nf)
                acc[mf][nf] = MFMA_BF16(af[mf], cur[nf], acc[mf][nf]);
        __builtin_amdgcn_s_setprio(0);
    }

#pragma unroll
    for (int half = 0; half < 2; ++half) {
        __syncthreads();
        if ((wid >> 1) == half) {
#pragma unroll
            for (int nf = 0; nf < 4; ++nf) {
                int col = wn + nf * 16 + lr;
                if (col >= 84) continue;
                float bv = (col < 81) ? bias[col] : 0.f;
#pragma unroll
                for (int mf = 0; mf < 4; ++mf)
#pragma unroll
                    for (int r = 0; r < 4; ++r) {
                        float vv = (col < 81) ? (acc[mf][nf][r] + bv) : 0.f;
                        Sb[mf * 16 + lg * 4 + r][col] = (bf16)vv;
                    }
            }
        }
        __syncthreads();
#pragma unroll
        for (int i = 0; i < 6; ++i) {
            int o = i * 256 + t;
            if (o < 64 * 21) {
                int row = o / 21, cq = (o - row * 21) * 4;
                *(bf16x4*)(outA + (size_t)(bm + half * 64 + row) * cAS + cq) =
                    *(const bf16x4*)&Sb[row][cq];
            }
        }
    }
}

// ---------------------------------------------------------------------------
// Generic k-loop GEMM, M=128: 1-barrier dbuf K-loop, bf16 residual stream.
// Sf overlays As/Bs (epilogue-only, barrier-separated) -> 40 KB, 4 blocks/CU.
// ---------------------------------------------------------------------------
template<bool OUTBF, bool RELU, bool RES, bool POS, bool LNOUT, bool TOUT>
__global__ __launch_bounds__(256) void k_gemm_res(const bf16* __restrict__ A,
                                                  const bf16* __restrict__ Wt,
                                                  const float* __restrict__ bias,
                                                  const bf16* __restrict__ resB,
                                                  bf16* __restrict__ outFB,
                                                  bf16* __restrict__ outB,
                                                  float* __restrict__ outT,
                                                  int K,
                                                  const float* __restrict__ ytab,
                                                  const float* __restrict__ xtab,
                                                  const float* __restrict__ lng,
                                                  const float* __restrict__ lnb,
                                                  bf16* __restrict__ xnbO)
{
    __shared__ __attribute__((aligned(16))) char smem[2 * 2 * 128 * 40 * sizeof(bf16)]; // 40960
    bf16 (*As)[128][40] = (bf16(*)[128][40])smem;             // [2][128][40], k-loop only
    bf16 (*Bs)[128][40] = (bf16(*)[128][40])(smem + 20480);   // [2][128][40], k-loop only
    float (*Sf)[136]    = (float(*)[136])smem;                // [64][136], epilogue only

    const int bm = blockIdx.x * 128;
    const int t = threadIdx.x;
    const int lane = t & 63, wid = t >> 6;
    const int wm = (wid >> 1) * 64, wn = (wid & 1) * 64;
    const int lr = lane & 15, lg = lane >> 4;

    const int r0 = t >> 2,          kg0 = (t & 3) * 8;
    const int r1 = (t + 256) >> 2,  kg1 = ((t + 256) & 3) * 8;

    const int nks = K >> 5;

    auto loadAW = [&](int k0, bf16x8* ra, bf16x8* rw) {
        ra[0] = *(const bf16x8*)(A  + (size_t)(bm + r0) * K + k0 + kg0);
        ra[1] = *(const bf16x8*)(A  + (size_t)(bm + r1) * K + k0 + kg1);
        rw[0] = *(const bf16x8*)(Wt + (size_t)r0 * K + k0 + kg0);
        rw[1] = *(const bf16x8*)(Wt + (size_t)r1 * K + k0 + kg1);
    };

    bf16x8 ra[2], rw[2];
    loadAW(0, ra, rw);
    *(bf16x8*)&As[0][r0][kg0] = ra[0];
    *(bf16x8*)&As[0][r1][kg1] = ra[1];
    *(bf16x8*)&Bs[0][r0][kg0] = rw[0];
    *(bf16x8*)&Bs[0][r1][kg1] = rw[1];
    if (nks > 1) loadAW(32, ra, rw);

    const f32x4 zero4 = {0.f, 0.f, 0.f, 0.f};
    f32x4 acc[4][4];
#pragma unroll
    for (int i = 0; i < 4; ++i)
#pragma unroll
        for (int j = 0; j < 4; ++j) acc[i][j] = zero4;

    for (int ks = 0; ks < nks; ++ks) {
        const int cur = ks & 1;
        __syncthreads();
        if (ks + 1 < nks) {
            *(bf16x8*)&As[cur ^ 1][r0][kg0] = ra[0];
            *(bf16x8*)&As[cur ^ 1][r1][kg1] = ra[1];
            *(bf16x8*)&Bs[cur ^ 1][r0][kg0] = rw[0];
            *(bf16x8*)&Bs[cur ^ 1][r1][kg1] = rw[1];
            if (ks + 2 < nks) loadAW((ks + 2) * 32, ra, rw);
        }
        bf16x8 af[4], bf[4];
#pragma unroll
        for (int mf = 0; mf < 4; ++mf)
            af[mf] = *(const bf16x8*)&As[cur][wm + mf*16 + lr][lg * 8];
#pragma unroll
        for (int nf = 0; nf < 4; ++nf)
            bf[nf] = *(const bf16x8*)&Bs[cur][wn + nf*16 + lr][lg * 8];
        __builtin_amdgcn_s_setprio(1);
#pragma unroll
        for (int mf = 0; mf < 4; ++mf)
#pragma unroll
            for (int nf = 0; nf < 4; ++nf)
                acc[mf][nf] = MFMA_BF16(af[mf], bf[nf], acc[mf][nf]);
        __builtin_amdgcn_s_setprio(0);
    }
    __syncthreads();

    if (OUTBF) {
        bf16 (*Sb)[136] = (bf16(*)[136])Sf;
#pragma unroll
        for (int nf = 0; nf < 4; ++nf) {
            int col = wn + nf * 16 + lr;
            float bv = bias ? bias[col] : 0.f;
#pragma unroll
            for (int mf = 0; mf < 4; ++mf)
#pragma unroll
                for (int r = 0; r < 4; ++r) {
                    float vv = acc[mf][nf][r] + bv;
                    if (RELU) vv = fmaxf(vv, 0.f);
                    Sb[wm + mf * 16 + lg * 4 + r][col] = (bf16)vv;
                }
        }
        __syncthreads();
#pragma unroll
        for (int i = 0; i < 8; ++i) {
            int o = i * 256 + t;
            int row = o >> 4, cg = (o & 15) * 8;
            *(bf16x8*)(outB + (size_t)(bm + row) * 128 + cg) = *(const bf16x8*)&Sb[row][cg];
        }
    } else {
        const int b_   = bm / cNPIX;
        const int hw0  = bm - b_ * cNPIX;
        for (int half = 0; half < 2; ++half) {
            __syncthreads();
            if ((wid >> 1) == half) {
#pragma unroll
                for (int nf = 0; nf < 4; ++nf) {
                    int col = wn + nf * 16 + lr;
                    float bv = bias ? bias[col] : 0.f;
#pragma unroll
                    for (int mf = 0; mf < 4; ++mf)
#pragma unroll
                        for (int r = 0; r < 4; ++r)
                            Sf[mf * 16 + lg * 4 + r][col] = acc[mf][nf][r] + bv;
                }
            }
            __syncthreads();
            if (!TOUT) {
#pragma unroll
                for (int i = 0; i < 8; ++i) {
                    int o = i * 256 + t;
                    int row = o >> 5, cq = (o & 31) * 4;
                    int grow = bm + half * 64 + row;
                    float4 v = *(const float4*)&Sf[row][cq];
                    if (POS) {
                        int hw = grow % cNPIX;
                        int h = hw / cW, w = hw - (hw / cW) * cW;
                        float4 p = (cq < 64) ? *(const float4*)(ytab + (h << 6) + cq)
                                             : *(const float4*)(xtab + (w << 6) + cq - 64);
                        v.x += p.x; v.y += p.y; v.z += p.z; v.w += p.w;
                    }
                    if (RES) {
                        bf16x4 rr = *(const bf16x4*)(resB + (size_t)grow * 128 + cq);
                        v.x += (float)rr[0]; v.y += (float)rr[1];
                        v.z += (float)rr[2]; v.w += (float)rr[3];
                    }
                    if (LNOUT) {
                        float s  = v.x + v.y + v.z + v.w;
                        float sq = v.x*v.x + v.y*v.y + v.z*v.z + v.w*v.w;
#pragma unroll
                        for (int mk = 1; mk < 32; mk <<= 1) {
                            s  += __shfl_xor(s,  mk);
                            sq += __shfl_xor(sq, mk);
                        }
                        float mu = s * (1.f / 128.f);
                        float rs = rsqrtf(sq * (1.f / 128.f) - mu * mu + 1e-5f);
                        float4 g4 = *(const float4*)(lng + cq);
                        float4 b4 = *(const float4*)(lnb + cq);
                        bf16x4 xo;
                        xo[0] = (bf16)((v.x - mu) * rs * g4.x + b4.x);
                        xo[1] = (bf16)((v.y - mu) * rs * g4.y + b4.y);
                        xo[2] = (bf16)((v.z - mu) * rs * g4.z + b4.z);
                        xo[3] = (bf16)((v.w - mu) * rs * g4.w + b4.w);
                        *(bf16x4*)(xnbO + (size_t)grow * 128 + cq) = xo;
                    }
                    bf16x4 fv;
                    fv[0] = (bf16)v.x; fv[1] = (bf16)v.y;
                    fv[2] = (bf16)v.z; fv[3] = (bf16)v.w;
                    *(bf16x4*)(outFB + (size_t)grow * 128 + cq) = fv;
                }
            } else {
#pragma unroll
                for (int i = 0; i < 8; ++i) {
                    int o = i * 256 + t;
                    int row = o >> 5, cq = (o & 31) * 4;
                    int grow = bm + half * 64 + row;
                    float4 v = *(const float4*)&Sf[row][cq];
                    bf16x4 rr = *(const bf16x4*)(resB + (size_t)grow * 128 + cq);
                    v.x += (float)rr[0]; v.y += (float)rr[1];
                    v.z += (float)rr[2]; v.w += (float)rr[3];
                    *(float4*)&Sf[row][cq] = v;
                }
                __syncthreads();
                const int lane16 = t & 15;
#pragma unroll
                for (int p = 0; p < 8; ++p) {
                    int col = p * 16 + (t >> 4);
                    float4 v;
                    v.x = Sf[lane16 * 4 + 0][col];
                    v.y = Sf[lane16 * 4 + 1][col];
                    v.z = Sf[lane16 * 4 + 2][col];
                    v.w = Sf[lane16 * 4 + 3][col];
                    *(float4*)(outT + ((size_t)(b_ * 128 + col)) * cNPIX
                               + hw0 + half * 64 + lane16 * 4) = v;
                }
            }
        }
    }
}

// ---------------------------------------------------------------------------
// Outlook fused gather (R14 structure: LDS-staged neighborhood).
// ---------------------------------------------------------------------------
__global__ __launch_bounds__(256) void k_olk_gather(const bf16* __restrict__ v,
                                                    const bf16* __restrict__ attn,
                                                    bf16* __restrict__ y)
{
    __shared__ bf16  Ls[100][136];
    __shared__ float pr[16][84];
    __shared__ float coef[16][26];

    const int t  = threadIdx.x;
    const int px = t >> 4;
    const int j  = t & 15;
    const int pix0 = blockIdx.x * 16;
    const int b   = pix0 / cNPIX;
    const int hw0 = pix0 % cNPIX;
    const int h   = hw0 / cW, w0 = hw0 % cW;
    const int pix = pix0 + px;
    const int w   = w0 + px;

    const size_t bbase = (size_t)b * cNPIX;

    for (int e = px; e < 100; e += 16) {
        const int a  = e / 20, cc = e - a * 20;
        const int sh = h + a - 2, sw = w0 + cc - 2;
        bf16x8 val;
        if ((unsigned)sh < (unsigned)cH && (unsigned)sw < (unsigned)cW) {
            val = *(const bf16x8*)(v + (bbase + (size_t)sh * cW + sw) * 128 + j * 8);
        } else {
#pragma unroll
            for (int q = 0; q < 8; ++q) val[q] = (bf16)0.f;
        }
        *(bf16x8*)&Ls[e][j * 8] = val;
    }

    if (j < 9) {
        const int p  = j;
        const int pi = p / 3, pj = p - pi * 3;
        const int hh = h + 1 - pi, ww = w + 1 - pj;
        float prv[9];
        if ((unsigned)hh < (unsigned)cH && (unsigned)ww < (unsigned)cW) {
            const size_t row = (size_t)(bbase + (size_t)hh * cW + ww);
            const bf16* arow = attn + row * cAS + p * 9;
            float lg[9];
            float m = 0.f;
#pragma unroll
            for (int q = 0; q < 9; ++q) { lg[q] = (float)arow[q]; m = fmaxf(m, lg[q]); }
            float se = 0.f;
#pragma unroll
            for (int q = 0; q < 9; ++q) { prv[q] = __expf(lg[q] - m); se += prv[q]; }
            float inv = 1.f / (se + __expf(-m));
#pragma unroll
            for (int q = 0; q < 9; ++q) prv[q] *= inv;
        } else {
#pragma unroll
            for (int q = 0; q < 9; ++q) prv[q] = 0.f;
        }
#pragma unroll
        for (int q = 0; q < 9; ++q) pr[px][p * 9 + q] = prv[q];
    }
    __syncthreads();

    for (int d = j; d < 25; d += 16) {
        const int a  = d / 5, bb = d - a * 5;
        float s = 0.f;
#pragma unroll
        for (int pi = 0; pi < 3; ++pi) {
            const int qi = pi + a - 2;
            if ((unsigned)qi >= 3u) continue;
#pragma unroll
            for (int pj = 0; pj < 3; ++pj) {
                const int qj = pj + bb - 2;
                if ((unsigned)qj >= 3u) continue;
                s += pr[px][(pi * 3 + pj) * 9 + qi * 3 + qj];
            }
        }
        coef[px][d] = s;
    }
    __syncthreads();

    float acc[8] = {};
#pragma unroll
    for (int a = 0; a < 5; ++a) {
#pragma unroll
        for (int bb = 0; bb < 5; ++bb) {
            const float cf = coef[px][a * 5 + bb];
            const bf16x8 v8 = *(const bf16x8*)&Ls[a * 20 + px + bb][j * 8];
#pragma unroll
            for (int e = 0; e < 8; ++e) acc[e] = fmaf(cf, (float)v8[e], acc[e]);
        }
    }
    bf16x8 o8;
#pragma unroll
    for (int e = 0; e < 8; ++e) o8[e] = (bf16)acc[e];
    *(bf16x8*)(y + (size_t)pix * 128 + j * 8) = o8;
}

// ---------------------------------------------------------------------------
// Depthwise 3x3 + bias + fast GELU.
// ---------------------------------------------------------------------------
__global__ __launch_bounds__(256) void k_dwconv_gelu(const bf16* __restrict__ h1,
                                                     const float* __restrict__ dwt,
                                                     const float* __restrict__ bdw,
                                                     bf16* __restrict__ h2)
{
    const int t   = threadIdx.x;
    const int c2  = t * 2;
    const int blk = blockIdx.x;
    const int row = blk >> 4;
    const int seg = blk & 15;
    const int bb  = row / cH, h = row % cH;
    const int w0  = seg * 20;

    float2 wgt[9];
#pragma unroll
    for (int k = 0; k < 9; ++k)
        wgt[k] = *(const float2*)(dwt + k * 512 + c2);
    if (h == 0) {
        wgt[0].x = wgt[0].y = wgt[1].x = wgt[1].y = wgt[2].x = wgt[2].y = 0.f;
    }
    if (h == cH - 1) {
        wgt[6].x = wgt[6].y = wgt[7].x = wgt[7].y = wgt[8].x = wgt[8].y = 0.f;
    }
    const float2 bias = *(const float2*)(bdw + c2);

    const size_t base = (size_t)bb * cNPIX;
    const int hm = (h == 0) ? 0 : h - 1;
    const int hp = (h == cH - 1) ? h : h + 1;
    const bf16* rp0 = h1 + (base + (size_t)hm * cW + w0) * 512 + c2;
    const bf16* rp1 = h1 + (base + (size_t)h  * cW + w0) * 512 + c2;
    const bf16* rp2 = h1 + (base + (size_t)hp * cW + w0) * 512 + c2;

    auto ldc = [&](const bf16* rp, int wofs) -> float2 {
        unsigned u = *(const unsigned*)(rp + (size_t)wofs * 512);
        float2 r;
        r.x = __uint_as_float(u << 16);
        r.y = __uint_as_float(u & 0xffff0000u);
        return r;
    };
    auto gelu = [](float x) -> float {
        float x2 = x * x;
        float z2 = fmaf(x2 * x, 0.0713548162726f, 1.5957691216057308f * x);
        float t1 = 1.f / (1.f + __expf(-z2));
        return x * t1;
    };

    float2 cm[3], c0[3], cp[3];
    if (seg == 0) {
#pragma unroll
        for (int r = 0; r < 3; ++r) { cm[r].x = 0.f; cm[r].y = 0.f; }
    } else {
        cm[0] = ldc(rp0, -1); cm[1] = ldc(rp1, -1); cm[2] = ldc(rp2, -1);
    }
    c0[0] = ldc(rp0, 0); c0[1] = ldc(rp1, 0); c0[2] = ldc(rp2, 0);

    bf16* op = h2 + (base + (size_t)h * cW + w0) * 512 + c2;

    for (int j = 0; j < 20; ++j) {
        if (j == 19 && seg == 15) {
#pragma unroll
            for (int r = 0; r < 3; ++r) { cp[r].x = 0.f; cp[r].y = 0.f; }
        } else {
            cp[0] = ldc(rp0, j + 1); cp[1] = ldc(rp1, j + 1); cp[2] = ldc(rp2, j + 1);
        }
        float a0 = bias.x, a1 = bias.y;
#pragma unroll
        for (int r = 0; r < 3; ++r) {
            a0 = fmaf(cm[r].x, wgt[r * 3 + 0].x, a0);
            a1 = fmaf(cm[r].y, wgt[r * 3 + 0].y, a1);
            a0 = fmaf(c0[r].x, wgt[r * 3 + 1].x, a0);
            a1 = fmaf(c0[r].y, wgt[r * 3 + 1].y, a1);
            a0 = fmaf(cp[r].x, wgt[r * 3 + 2].x, a0);
            a1 = fmaf(cp[r].y, wgt[r * 3 + 2].y, a1);
        }
        a0 = gelu(a0);
        a1 = gelu(a1);
        union { bf16 hh[2]; unsigned int u; } o2;
        o2.hh[0] = (bf16)a0;
        o2.hh[1] = (bf16)a1;
        *(unsigned int*)(op + (size_t)j * 512) = o2.u;
#pragma unroll
        for (int r = 0; r < 3; ++r) { cm[r] = c0[r]; c0[r] = cp[r]; }
    }
}

// ---------------------------------------------------------------------------
// Window attention (8-wave, dbuf, 1 barrier/tile).
// ---------------------------------------------------------------------------
template<bool SHIFT>
__global__ __launch_bounds__(512) void k_win_attn(const bf16* __restrict__ q,
                                                  const bf16* __restrict__ ks,
                                                  const bf16* __restrict__ vt,
                                                  bf16* __restrict__ out)
{
    __shared__ bf16 Ks[2][32][136];
    __shared__ bf16 Vs[2][128][44];
    __shared__ bf16 Ps[8][16][44];

    const int t = threadIdx.x, lane = t & 63, wid = t >> 6;
    const int lr = lane & 15, lg = lane >> 4;
    const int wb = blockIdx.x;
    const int b  = wb >> 6, win = wb & 63;
    const int nh = win >> 3, nw = win & 7;
    const int qbase = blockIdx.y * 128 + wid * 16;

    const float SCALE   = 0.088388347648318447f;
    const float MASKRAW = 100.f / 0.088388347648318447f;

    auto tokOf = [&](int p) {
        int ph = nh * 12 + p / 40;
        int pw = nw * 40 + (p % 40);
        if (SHIFT) {
            ph += 6;  if (ph >= cH) ph -= cH;
            pw += 20; if (pw >= cW) pw -= cW;
        }
        return b * cNPIX + ph * cW + pw;
    };

    int qp = min(qbase + lr, 479);
    const bf16* qptr = q + (size_t)tokOf(qp) * 128;
    bf16x8 qf[4];
#pragma unroll
    for (int c = 0; c < 4; ++c)
        qf[c] = *(const bf16x8*)(qptr + c * 32 + lg * 8);

    int labq[4];
    if (SHIFT) {
#pragma unroll
        for (int r = 0; r < 4; ++r) {
            int qrow = min(qbase + lg * 4 + r, 479);
            int qr = qrow / 40, qc = qrow - qr * 40;
            int rh = (nh == 7) ? (qr < 6 ? 1 : 2) : 0;
            int rc = (nw == 7) ? (qc < 20 ? 1 : 2) : 0;
            labq[r] = rh * 3 + rc;
        }
    }

    const bf16* kbase = ks + (size_t)wb * 480 * 128;
    const bf16* vbase = vt + (size_t)wb * 128 * 480;
    auto loadK = [&](int kt) {
        return *(const bf16x8*)(kbase + (size_t)(kt * 32 + (t >> 4)) * 128 + (t & 15) * 8);
    };
    auto loadV = [&](int kt) {
        return *(const bf16x8*)(vbase + (size_t)(t >> 2) * 480 + kt * 32 + (t & 3) * 8);
    };

    bf16x8 kreg = loadK(0);
    bf16x8 vreg = loadV(0);
    *(bf16x8*)&Ks[0][t >> 4][(t & 15) * 8] = kreg;
    *(bf16x8*)&Vs[0][t >> 2][(t & 3) * 8]  = vreg;
    kreg = loadK(1);
    vreg = loadV(1);

    int kc0 = lr, kr0 = 0;
    int kc1 = 16 + lr, kr1 = 0;

    const f32x4 zero4 = {0.f, 0.f, 0.f, 0.f};
    float m_run[4] = {0.f, 0.f, 0.f, 0.f};
    float mguard = 8.f;
    f32x4 l4 = zero4;
    f32x4 o[8];
#pragma unroll
    for (int nf = 0; nf < 8; ++nf) o[nf] = zero4;

    bf16x8 ones8;
#pragma unroll
    for (int j = 0; j < 8; ++j) ones8[j] = (bf16)1.f;

    for (int kt = 0; kt < 15; ++kt) {
        const int cur = kt & 1;
        __syncthreads();
        if (kt + 1 < 15) {
            *(bf16x8*)&Ks[cur ^ 1][t >> 4][(t & 15) * 8] = kreg;
            *(bf16x8*)&Vs[cur ^ 1][t >> 2][(t & 3) * 8]  = vreg;
            if (kt + 2 < 15) {
                kreg = loadK(kt + 2);
                vreg = loadV(kt + 2);
            }
        }

        f32x4 s0 = zero4, s1 = zero4;
        __builtin_amdgcn_s_setprio(1);
#pragma unroll
        for (int c = 0; c < 4; ++c) {
            bf16x8 kf0 = *(const bf16x8*)&Ks[cur][lr][c * 32 + lg * 8];
            bf16x8 kf1 = *(const bf16x8*)&Ks[cur][16 + lr][c * 32 + lg * 8];
            s0 = MFMA_BF16(qf[c], kf0, s0);
            s1 = MFMA_BF16(qf[c], kf1, s1);
        }
        __builtin_amdgcn_s_setprio(0);

        if (SHIFT) {
            int rh0 = (nh == 7) ? (kr0 < 6 ? 1 : 2) : 0;
            int rc0 = (nw == 7) ? (kc0 < 20 ? 1 : 2) : 0;
            int rh1 = (nh == 7) ? (kr1 < 6 ? 1 : 2) : 0;
            int rc1 = (nw == 7) ? (kc1 < 20 ? 1 : 2) : 0;
            int lab0 = rh0 * 3 + rc0;
            int lab1 = rh1 * 3 + rc1;
#pragma unroll
            for (int r = 0; r < 4; ++r) {
                if (labq[r] != lab0) s0[r] -= MASKRAW;
                if (labq[r] != lab1) s1[r] -= MASKRAW;
            }
        }
        kc0 += 32; if (kc0 >= 40) { kc0 -= 40; ++kr0; }
        kc1 += 32; if (kc1 >= 40) { kc1 -= 40; ++kr1; }

        float tm = fmaxf(fmaxf(fmaxf(s0[0], s0[1]), fmaxf(s0[2], s0[3])),
                         fmaxf(fmaxf(s1[0], s1[1]), fmaxf(s1[2], s1[3])));
        if (__any(tm * SCALE > mguard)) {
#pragma unroll
            for (int r = 0; r < 4; ++r) {
                float mx = fmaxf(s0[r], s1[r]);
#pragma unroll
                for (int off = 1; off < 16; off <<= 1) mx = fmaxf(mx, __shfl_xor(mx, off));
                float nm = fmaxf(m_run[r], mx * SCALE);
                float sc = __expf(m_run[r] - nm);
#pragma unroll
                for (int nf = 0; nf < 8; ++nf) o[nf][r] *= sc;
                l4[r] *= sc;
                m_run[r] = nm;
            }
            mguard = fminf(fminf(m_run[0], m_run[1]), fminf(m_run[2], m_run[3])) + 8.f;
        }

#pragma unroll
        for (int r = 0; r < 4; ++r) {
            float p0 = __expf(fmaf(s0[r], SCALE, -m_run[r]));
            float p1 = __expf(fmaf(s1[r], SCALE, -m_run[r]));
            Ps[wid][lg * 4 + r][lr]      = (bf16)p0;
            Ps[wid][lg * 4 + r][16 + lr] = (bf16)p1;
        }

        bf16x8 pa = *(const bf16x8*)&Ps[wid][lr][lg * 8];
        __builtin_amdgcn_s_setprio(1);
        l4 = MFMA_BF16(pa, ones8, l4);
#pragma unroll
        for (int nf = 0; nf < 8; ++nf) {
            bf16x8 bv = *(const bf16x8*)&Vs[cur][nf * 16 + lr][lg * 8];
            o[nf] = MFMA_BF16(pa, bv, o[nf]);
        }
        __builtin_amdgcn_s_setprio(0);
    }

#pragma unroll
    for (int r = 0; r < 4; ++r) {
        int qrow = qbase + lg * 4 + r;
        if (qrow >= 480) continue;
        float inv = 1.f / (l4[r] + __expf(-m_run[r]));
        size_t ooff = (size_t)tokOf(qrow) * 128;
#pragma unroll
        for (int nf = 0; nf < 8; ++nf)
            out[ooff + nf * 16 + lr] = (bf16)(o[nf][r] * inv);
    }
}

// ---------------------------------------------------------------------------
// Host launcher
// ---------------------------------------------------------------------------
extern "C" void kernel_launch(void* const* d_in, const int* in_sizes, int n_in,
                              void* d_out, int out_size, void* d_ws, size_t ws_size,
                              hipStream_t stream)
{
    (void)in_sizes; (void)n_in; (void)out_size; (void)ws_size;

    const float* X = (const float*)d_in[0];

    char* ws = (char*)d_ws;
    bf16*  f    = (bf16*)ws;                                  ws += (size_t)cNTOK * 128 * 2;
    bf16*  xnb  = (bf16*)ws;                                  ws += (size_t)cNTOK * 128 * 2;
    bf16*  bufA = (bf16*)ws;                                  ws += (size_t)cNTOK * 512 * 2;
    bf16*  bufB = (bf16*)ws;                                  ws += (size_t)cNTOK * 512 * 2;
    bf16*  wts  = (bf16*)ws;

    size_t wo_off = 0;
    auto nextw = [&](int K, int M) { bf16* p = wts + wo_off; wo_off += (size_t)K * M; return p; };
    bf16* agg_w1t = nextw(256, 128);
    bf16* agg_w2t = nextw(128, 128);
    bf16* ol_wvt  = nextw(128, 128);
    bf16* ol_wat  = nextw(128, 81);
    bf16* ol_wot  = nextw(128, 128);
    bf16* f1_w1t  = nextw(128, 512);
    bf16* f1_w2t  = nextw(512, 128);
    bf16* w_qkvt  = nextw(128, 384);
    bf16* w_wot   = nextw(128, 128);
    bf16* f2_w1t  = nextw(128, 512);
    bf16* f2_w2t  = nextw(512, 128);
    bf16* s_qkvt  = nextw(128, 384);
    bf16* s_wot   = nextw(128, 128);
    bf16* f3_w1t  = nextw(128, 512);
    bf16* f3_w2t  = nextw(512, 128);
    float* dwt1 = (float*)(wts + wo_off);
    float* dwt2 = dwt1 + 512 * 9;
    float* dwt3 = dwt2 + 512 * 9;
    float* ytab = dwt3 + 512 * 9;
    float* xtab = ytab + 96 * 64;

    WJobs jobs;
    int ji = 0;
    auto addj = [&](int src_idx, bf16* dst, int K, int M) {
        jobs.j[ji++] = WJob{(const float*)d_in[src_idx], dst, K, M};
    };
    addj(1,  agg_w1t, 256, 128);
    addj(3,  agg_w2t, 128, 128);
    addj(7,  ol_wvt,  128, 128);
    addj(8,  ol_wat,  128, 81);
    addj(10, ol_wot,  128, 128);
    addj(14, f1_w1t,  128, 512);
    addj(18, f1_w2t,  512, 128);
    addj(22, w_qkvt,           128, 128);
    addj(23, w_qkvt + 128*128, 128, 128);
    addj(24, w_qkvt + 256*128, 128, 128);
    addj(25, w_wot,   128, 128);
    addj(29, f2_w1t,  128, 512);
    addj(33, f2_w2t,  512, 128);
    addj(37, s_qkvt,           128, 128);
    addj(38, s_qkvt + 128*128, 128, 128);
    addj(39, s_qkvt + 256*128, 128, 128);
    addj(40, s_wot,   128, 128);
    addj(44, f3_w1t,  128, 512);
    addj(48, f3_w2t,  512, 128);
    k_wt<<<dim3(16, 16, 19), dim3(32, 8), 0, stream>>>(jobs);
    k_dwt<<<3, 256, 0, stream>>>((const float*)d_in[16], (const float*)d_in[31],
                                 (const float*)d_in[46], dwt1, dwt2, dwt3);
    k_postab<<<80, 256, 0, stream>>>(ytab, xtab);

    const int nTT = cNTOK / 128;   // 480 token tiles

    // ---- input transpose + aggregation MLP (agg_w2 epilogue emits ol-LN) ----
    k_chw2hwc<<<dim3(cNPIX / 32, 256 / 32, cB), dim3(32, 8), 0, stream>>>(X, bufA);
    k_gemm_res<true, true, false, false, false, false><<<nTT, 256, 0, stream>>>(
        bufA, agg_w1t, (const float*)d_in[2], nullptr, nullptr, bufB, nullptr, 256,
        nullptr, nullptr, nullptr, nullptr, nullptr);
    k_gemm_res<false, false, false, false, true, false><<<nTT, 256, 0, stream>>>(
        bufB, agg_w2t, (const float*)d_in[4], nullptr, f, nullptr, nullptr, 128,
        nullptr, nullptr, (const float*)d_in[5], (const float*)d_in[6], xnb);

    // ---- outlook attention (ol_wo epilogue emits f1-LN) ----
    {
        bf16*  vb   = bufA;
        bf16*  gout = bufA + (size_t)cNTOK * 128;
        bf16*  atn  = bufB;
        k_gemm128<-1><<<nTT, 256, 0, stream>>>(xnb, ol_wvt, nullptr, vb, 128, nullptr, nullptr);
        k_gemm128_wa<<<nTT, 256, 0, stream>>>(xnb, ol_wat, (const float*)d_in[9], atn);
        k_olk_gather<<<cNTOK / 16, 256, 0, stream>>>(vb, atn, gout);
        k_gemm_res<false, false, true, false, true, false><<<nTT, 256, 0, stream>>>(
            gout, ol_wot, (const float*)d_in[11], f, f, nullptr, nullptr, 128,
            nullptr, nullptr, (const float*)d_in[12], (const float*)d_in[13], xnb);
    }

    // ---- conv FFN; w2 epilogue emits next block's LN (if lnG), or the
    //      transposed final output (f3) ----
    auto run_ffn = [&](int base, bf16* w1t, bf16* w2t, float* dwt, bool pos,
                       const float* lnG, const float* lnB, float* outT) {
        k_gemm128<-1><<<nTT * 4, 256, 0, stream>>>(
            xnb, w1t, (const float*)d_in[base + 3], bufA, 512, nullptr, nullptr);
        k_dwconv_gelu<<<cB * cH * 16, 256, 0, stream>>>(
            bufA, dwt, (const float*)d_in[base + 5], bufB);
        if (pos) {
            k_gemm_res<false, false, true, true, true, false><<<nTT, 256, 0, stream>>>(
                bufB, w2t, (const float*)d_in[base + 7], f, f, nullptr, nullptr, 512,
                ytab, xtab, lnG, lnB, xnb);
        } else if (lnG) {
            k_gemm_res<false, false, true, false, true, false><<<nTT, 256, 0, stream>>>(
                bufB, w2t, (const float*)d_in[base + 7], f, f, nullptr, nullptr, 512,
                nullptr, nullptr, lnG, lnB, xnb);
        } else {
            k_gemm_res<false, false, true, false, false, true><<<nTT, 256, 0, stream>>>(
                bufB, w2t, (const float*)d_in[base + 7], f, nullptr, nullptr, outT, 512,
                nullptr, nullptr, nullptr, nullptr, nullptr);
        }
    };

    // ---- window attention; wo epilogue emits next block's LN ----
    auto run_win = [&](int base, bf16* qkvt, bf16* wot, bool shift,
                       const float* lnG, const float* lnB) {
        bf16* qb  = bufA;
        bf16* ksb = bufA + (size_t)cNTOK * 128;
        bf16* vtb = bufA + (size_t)cNTOK * 256;
        bf16* ao  = bufB;
        if (shift)
            k_gemm128<1><<<nTT * 3, 256, 0, stream>>>(xnb, qkvt, nullptr, qb, 384, vtb, ksb);
        else
            k_gemm128<0><<<nTT * 3, 256, 0, stream>>>(xnb, qkvt, nullptr, qb, 384, vtb, ksb);
        if (shift) k_win_attn<true ><<<dim3(128, 4), 512, 0, stream>>>(qb, ksb, vtb, ao);
        else       k_win_attn<false><<<dim3(128, 4), 512, 0, stream>>>(qb, ksb, vtb, ao);
        k_gemm_res<false, false, true, false, true, false><<<nTT, 256, 0, stream>>>(
            ao, wot, (const float*)d_in[base + 6], f, f, nullptr, nullptr, 128,
            nullptr, nullptr, lnG, lnB, xnb);
    };

    run_ffn(12, f1_w1t, f1_w2t, dwt1, true,
            (const float*)d_in[20], (const float*)d_in[21], nullptr);   // f1
    run_win(20, w_qkvt, w_wot, false,
            (const float*)d_in[27], (const float*)d_in[28]);            // w
    run_ffn(27, f2_w1t, f2_w2t, dwt2, false,
            (const float*)d_in[35], (const float*)d_in[36], nullptr);   // f2
    run_win(35, s_qkvt, s_wot, true,
            (const float*)d_in[42], (const float*)d_in[43]);            // s
    run_ffn(42, f3_w1t, f3_w2t, dwt3, false, nullptr, nullptr,
            (float*)d_out);                                             // f3 -> d_out^T
}

// Round 22
// 502.573 us; speedup vs baseline: 1.0568x; 1.0202x over previous
//
#include <hip/hip_runtime.h>

typedef __bf16 bf16;
typedef __bf16 bf16x8 __attribute__((ext_vector_type(8)));
typedef __bf16 bf16x4 __attribute__((ext_vector_type(4)));
typedef float  f32x4  __attribute__((ext_vector_type(4)));

#define MFMA_BF16(a, b, c) __builtin_amdgcn_mfma_f32_16x16x32_bf16(a, b, c, 0, 0, 0)

constexpr int cB    = 2;
constexpr int cH    = 96;
constexpr int cW    = 320;
constexpr int cC    = 128;
constexpr int cNPIX = cH * cW;          // 30720
constexpr int cNTOK = cB * cNPIX;       // 61440
constexpr int cAS   = 84;               // padded attn-logit stride (81 -> 84)

// ---------------------------------------------------------------------------
// Weight transpose+convert: fp32 W (K x M) -> bf16 Wt (M x K)
// ---------------------------------------------------------------------------
struct WJob  { const float* src; bf16* dst; int K; int M; };
struct WJobs { WJob j[19]; };

__global__ __launch_bounds__(256) void k_wt(WJobs jobs)
{
    __shared__ float tile[32][33];
    const WJob jb = jobs.j[blockIdx.z];
    int k0 = blockIdx.y * 32, m0 = blockIdx.x * 32;
    if (k0 >= jb.K || m0 >= jb.M) return;
    int tx = threadIdx.x, ty = threadIdx.y;
#pragma unroll
    for (int i = 0; i < 32; i += 8) {
        int kk = k0 + ty + i, mm = m0 + tx;
        tile[ty + i][tx] = (kk < jb.K && mm < jb.M) ? jb.src[(size_t)kk * jb.M + mm] : 0.f;
    }
    __syncthreads();
#pragma unroll
    for (int i = 0; i < 32; i += 8) {
        int mm = m0 + ty + i, kk = k0 + tx;
        if (mm < jb.M && kk < jb.K)
            jb.dst[(size_t)mm * jb.K + kk] = (bf16)tile[tx][ty + i];
    }
}

__global__ __launch_bounds__(256) void k_dwt(const float* s0, const float* s1, const float* s2,
                                             float* d0, float* d1, float* d2)
{
    const float* s = blockIdx.x == 0 ? s0 : (blockIdx.x == 1 ? s1 : s2);
    float*       d = blockIdx.x == 0 ? d0 : (blockIdx.x == 1 ? d1 : d2);
    for (int i = threadIdx.x; i < 512 * 9; i += 256) {
        int c = i / 9, tap = i - c * 9;
        d[tap * 512 + c] = s[i];
    }
}

__global__ __launch_bounds__(256) void k_postab(float* __restrict__ yt, float* __restrict__ xt)
{
    int i = blockIdx.x * 256 + threadIdx.x;
    const float TWO_PI = 6.283185307179586f;
    const float KSC = -9.210340371976184f / 32.f;
    if (i < 96 * 64) {
        int h = i >> 6, c = i & 63;
        float p = (float)(h + 1) * (TWO_PI / (96.f + 1e-6f));
        float val = p * expf((float)(c >> 1) * KSC);
        yt[i] = (c & 1) ? cosf(val) : sinf(val);
    }
    if (i < 320 * 64) {
        int w = i >> 6, c = i & 63;
        float p = (float)(w + 1) * (TWO_PI / (320.f + 1e-6f));
        float val = p * expf((float)(c >> 1) * KSC);
        xt[i] = (c & 1) ? cosf(val) : sinf(val);
    }
}

// ---------------------------------------------------------------------------
// Fused input-transpose + aggregation w1 GEMM (K=256, fp32 X in CHW layout).
// A-staging reads X rows (contiguous along HW), converts to bf16, writes LDS
// transposed. Replaces k_chw2hwc + the K=256 k_gemm_res instance.
// ---------------------------------------------------------------------------
__global__ __launch_bounds__(256) void k_gemm_agg(const float* __restrict__ X,
                                                  const bf16* __restrict__ Wt,
                                                  const float* __restrict__ bias,
                                                  bf16* __restrict__ outB)
{
    __shared__ __attribute__((aligned(16))) char smem[40960];
    bf16 (*As)[128][40] = (bf16(*)[128][40])smem;             // [2][128][40], k-loop
    bf16 (*Bs)[128][40] = (bf16(*)[128][40])(smem + 20480);   // [2][128][40], k-loop
    bf16 (*Sb)[136]     = (bf16(*)[136])smem;                 // epilogue overlay

    const int bm  = blockIdx.x * 128;
    const int b_  = bm / cNPIX;
    const int hw0 = bm - b_ * cNPIX;

    const int t = threadIdx.x;
    const int lane = t & 63, wid = t >> 6;
    const int wm = (wid >> 1) * 64, wn = (wid & 1) * 64;
    const int lr = lane & 15, lg = lane >> 4;

    // A staging: thread covers C-row (k0+kk), 16 floats at hw offset l8*16
    const int kk = t & 31, l8 = t >> 5;
    const float* xbase = X + (size_t)b_ * 256 * cNPIX + hw0 + l8 * 16;

    // W staging (rows 0..127, K=256)
    const int r0 = t >> 2,          kg0 = (t & 3) * 8;
    const int r1 = (t + 256) >> 2,  kg1 = ((t + 256) & 3) * 8;

    auto loadA = [&](int k0, float4* rx) {
        const float* p = xbase + (size_t)(k0 + kk) * cNPIX;
#pragma unroll
        for (int j = 0; j < 4; ++j) rx[j] = *(const float4*)(p + j * 4);
    };
    auto loadW = [&](int k0, bf16x8* rw) {
        rw[0] = *(const bf16x8*)(Wt + (size_t)r0 * 256 + k0 + kg0);
        rw[1] = *(const bf16x8*)(Wt + (size_t)r1 * 256 + k0 + kg1);
    };
    auto storeAW = [&](int buf, const float4* rx, const bf16x8* rw) {
#pragma unroll
        for (int j = 0; j < 4; ++j) {
            As[buf][l8 * 16 + j * 4 + 0][kk] = (bf16)rx[j].x;
            As[buf][l8 * 16 + j * 4 + 1][kk] = (bf16)rx[j].y;
            As[buf][l8 * 16 + j * 4 + 2][kk] = (bf16)rx[j].z;
            As[buf][l8 * 16 + j * 4 + 3][kk] = (bf16)rx[j].w;
        }
        *(bf16x8*)&Bs[buf][r0][kg0] = rw[0];
        *(bf16x8*)&Bs[buf][r1][kg1] = rw[1];
    };

    float4 rx[4]; bf16x8 rw[2];
    loadA(0, rx); loadW(0, rw);
    storeAW(0, rx, rw);
    loadA(32, rx); loadW(32, rw);

    const f32x4 zero4 = {0.f, 0.f, 0.f, 0.f};
    f32x4 acc[4][4];
#pragma unroll
    for (int i = 0; i < 4; ++i)
#pragma unroll
        for (int j = 0; j < 4; ++j) acc[i][j] = zero4;

    for (int ks = 0; ks < 8; ++ks) {
        const int cur = ks & 1;
        __syncthreads();
        if (ks + 1 < 8) {
            storeAW(cur ^ 1, rx, rw);
            if (ks + 2 < 8) { loadA((ks + 2) * 32, rx); loadW((ks + 2) * 32, rw); }
        }
        bf16x8 af[4], bf[4];
#pragma unroll
        for (int mf = 0; mf < 4; ++mf)
            af[mf] = *(const bf16x8*)&As[cur][wm + mf*16 + lr][lg * 8];
#pragma unroll
        for (int nf = 0; nf < 4; ++nf)
            bf[nf] = *(const bf16x8*)&Bs[cur][wn + nf*16 + lr][lg * 8];
        __builtin_amdgcn_s_setprio(1);
#pragma unroll
        for (int mf = 0; mf < 4; ++mf)
#pragma unroll
            for (int nf = 0; nf < 4; ++nf)
                acc[mf][nf] = MFMA_BF16(af[mf], bf[nf], acc[mf][nf]);
        __builtin_amdgcn_s_setprio(0);
    }
    __syncthreads();

    // bias + ReLU epilogue -> bf16 out (128 cols)
#pragma unroll
    for (int nf = 0; nf < 4; ++nf) {
        int col = wn + nf * 16 + lr;
        float bv = bias[col];
#pragma unroll
        for (int mf = 0; mf < 4; ++mf)
#pragma unroll
            for (int r = 0; r < 4; ++r)
                Sb[wm + mf * 16 + lg * 4 + r][col] = (bf16)fmaxf(acc[mf][nf][r] + bv, 0.f);
    }
    __syncthreads();
#pragma unroll
    for (int i = 0; i < 8; ++i) {
        int o = i * 256 + t;
        int row = o >> 4, cg = (o & 15) * 8;
        *(bf16x8*)(outB + (size_t)(bm + row) * 128 + cg) = *(const bf16x8*)&Sb[row][cg];
    }
}

// ---------------------------------------------------------------------------
// K=128 single-shot GEMM. LDS: Sb overlays As (barrier-separated lifetimes).
// ---------------------------------------------------------------------------
template<int QKVS>
__global__ __launch_bounds__(256) void k_gemm128(const bf16* __restrict__ A,
                                                 const bf16* __restrict__ Wt,
                                                 const float* __restrict__ bias,
                                                 bf16* __restrict__ outB, int M,
                                                 bf16* __restrict__ vtb,
                                                 bf16* __restrict__ ksb)
{
    __shared__ __attribute__((aligned(16))) char smem[128 * 136 * sizeof(bf16)];
    bf16 (*As)[136] = (bf16(*)[136])smem;   // live: staging + k-loop
    bf16 (*Sb)[136] = (bf16(*)[136])smem;   // live: epilogue (post-barrier)

    const int NS = M >> 7;
    const int l  = blockIdx.x;
    const int r8 = l % (8 * NS);
    const int qq = l / (8 * NS);
    const int bm = (qq * 8 + (r8 & 7)) * 128;
    const int bn = (r8 >> 3) * 128;

    const int t = threadIdx.x;
    const int lane = t & 63, wid = t >> 6;
    const int wm = (wid >> 1) * 64, wn = (wid & 1) * 64;
    const int lr = lane & 15, lg = lane >> 4;

    const bf16* wp = Wt + (size_t)(bn + wn + lr) * 128 + lg * 8;
    bf16x8 bwA[4], bwB[4];
#pragma unroll
    for (int nf = 0; nf < 4; ++nf)
        bwA[nf] = *(const bf16x8*)(wp + (size_t)(nf * 16) * 128);

#pragma unroll
    for (int i = 0; i < 8; ++i) {
        int o = i * 256 + t;
        int row = o >> 4, cg = (o & 15) * 8;
        *(bf16x8*)&As[row][cg] = *(const bf16x8*)(A + (size_t)(bm + row) * 128 + cg);
    }
    __syncthreads();

    const f32x4 zero4 = {0.f, 0.f, 0.f, 0.f};
    f32x4 acc[4][4];
#pragma unroll
    for (int i = 0; i < 4; ++i)
#pragma unroll
        for (int j = 0; j < 4; ++j) acc[i][j] = zero4;

#pragma unroll
    for (int ks = 0; ks < 4; ++ks) {
        const bf16x8* cur = (ks & 1) ? bwB : bwA;
        bf16x8*       nxt = (ks & 1) ? bwA : bwB;
        if (ks < 3) {
#pragma unroll
            for (int nf = 0; nf < 4; ++nf)
                nxt[nf] = *(const bf16x8*)(wp + (size_t)(nf * 16) * 128 + (ks + 1) * 32);
        }
        bf16x8 af[4];
#pragma unroll
        for (int mf = 0; mf < 4; ++mf)
            af[mf] = *(const bf16x8*)&As[wm + mf*16 + lr][ks*32 + lg*8];
        __builtin_amdgcn_s_setprio(1);
#pragma unroll
        for (int mf = 0; mf < 4; ++mf)
#pragma unroll
            for (int nf = 0; nf < 4; ++nf)
                acc[mf][nf] = MFMA_BF16(af[mf], cur[nf], acc[mf][nf]);
        __builtin_amdgcn_s_setprio(0);
    }

    const bool vpart = (QKVS >= 0) && (bn == 256);
    const bool kpart = (QKVS >= 0) && (bn == 128);
    if (!vpart) {
#pragma unroll
        for (int half = 0; half < 2; ++half) {
            __syncthreads();
            if ((wid >> 1) == half) {
#pragma unroll
                for (int nf = 0; nf < 4; ++nf) {
                    int col = wn + nf * 16 + lr;
                    float bv = bias ? bias[bn + col] : 0.f;
#pragma unroll
                    for (int mf = 0; mf < 4; ++mf)
#pragma unroll
                        for (int r = 0; r < 4; ++r)
                            Sb[mf * 16 + lg * 4 + r][col] = (bf16)(acc[mf][nf][r] + bv);
                }
            }
            __syncthreads();
            if (!kpart) {
                const int ldo = (QKVS >= 0) ? 128 : M;
#pragma unroll
                for (int i = 0; i < 4; ++i) {
                    int o = i * 256 + t;
                    int row = o >> 4, cg = (o & 15) * 8;
                    *(bf16x8*)(outB + (size_t)(bm + half * 64 + row) * ldo + bn + cg) =
                        *(const bf16x8*)&Sb[row][cg];
                }
            } else {
#pragma unroll
                for (int i = 0; i < 4; ++i) {
                    int o = i * 256 + t;
                    int row = o >> 4, cg = (o & 15) * 8;
                    int gt = bm + half * 64 + row;
                    int b_ = gt / cNPIX, hw = gt - b_ * cNPIX;
                    int h = hw / cW, w = hw - (hw / cW) * cW;
                    int h0 = (QKVS == 1) ? ((h + 90) % 96)  : h;
                    int w0 = (QKVS == 1) ? ((w + 300) % 320) : w;
                    int nh = h0 / 12, kh = h0 - nh * 12;
                    int nw = w0 / 40, kw = w0 - nw * 40;
                    size_t krow = (size_t)((b_ * 64 + nh * 8 + nw) * 480 + kh * 40 + kw);
                    *(bf16x8*)(ksb + krow * 128 + cg) = *(const bf16x8*)&Sb[row][cg];
                }
            }
        }
    } else {
        const int lr_ = t & 15, cg_ = t >> 4;
        const int gt = bm + lr_ * 8;
        const int b_ = gt / cNPIX, hw = gt % cNPIX;
        const int h = hw / cW, w = hw % cW;
        const int h0 = (QKVS == 1) ? ((h + 90) % 96) : h;
        const int nh = h0 / 12, kh = h0 - nh * 12;
#pragma unroll
        for (int cp = 0; cp < 2; ++cp) {
            __syncthreads();
            if ((wid & 1) == cp) {
#pragma unroll
                for (int nf = 0; nf < 4; ++nf) {
                    int cl = nf * 16 + lr;
#pragma unroll
                    for (int mf = 0; mf < 4; ++mf)
#pragma unroll
                        for (int r = 0; r < 4; ++r)
                            Sb[cl][wm + mf * 16 + lg * 4 + r] = (bf16)acc[mf][nf][r];
                }
            }
            __syncthreads();
#pragma unroll
            for (int i = 0; i < 4; ++i) {
                int chl = cg_ + 16 * i;
                int ch  = cp * 64 + chl;
                bf16x8 e = *(const bf16x8*)&Sb[chl][lr_ * 8];
#pragma unroll
                for (int hi = 0; hi < 2; ++hi) {
                    int wv = (QKVS == 1) ? ((w + hi * 4 + 300) % 320) : (w + hi * 4);
                    int nw = wv / 40, kw = wv - nw * 40;
                    bf16* dst = vtb + ((size_t)((b_ * 64 + nh * 8 + nw) * 128 + ch)) * 480 + kh * 40 + kw;
                    bf16x4 hv;
#pragma unroll
                    for (int j = 0; j < 4; ++j) hv[j] = e[hi * 4 + j];
                    *(bf16x4*)dst = hv;
                }
            }
        }
    }
}

// ---------------------------------------------------------------------------
// K=128 GEMM for outlook attn logits: M=81 (stride 84). Sb overlays As.
// ---------------------------------------------------------------------------
__global__ __launch_bounds__(256) void k_gemm128_wa(const bf16* __restrict__ A,
                                                    const bf16* __restrict__ Wt,
                                                    const float* __restrict__ bias,
                                                    bf16* __restrict__ outA)
{
    __shared__ __attribute__((aligned(16))) char smem[128 * 136 * sizeof(bf16)];
    bf16 (*As)[136] = (bf16(*)[136])smem;
    bf16 (*Sb)[88]  = (bf16(*)[88])smem;

    const int bm = blockIdx.x * 128;
    const int t = threadIdx.x;
    const int lane = t & 63, wid = t >> 6;
    const int wm = (wid >> 1) * 64, wn = (wid & 1) * 64;
    const int lr = lane & 15, lg = lane >> 4;

    bf16x8 zrow;
#pragma unroll
    for (int j = 0; j < 8; ++j) zrow[j] = (bf16)0.f;

    bool okc[4];
    const bf16* wp = Wt + (size_t)(wn + lr) * 128 + lg * 8;
#pragma unroll
    for (int nf = 0; nf < 4; ++nf) okc[nf] = (wn + nf * 16 + lr) < 81;

    bf16x8 bwA[4], bwB[4];
#pragma unroll
    for (int nf = 0; nf < 4; ++nf)
        bwA[nf] = okc[nf] ? *(const bf16x8*)(wp + (size_t)(nf * 16) * 128) : zrow;

#pragma unroll
    for (int i = 0; i < 8; ++i) {
        int o = i * 256 + t;
        int row = o >> 4, cg = (o & 15) * 8;
        *(bf16x8*)&As[row][cg] = *(const bf16x8*)(A + (size_t)(bm + row) * 128 + cg);
    }
    __syncthreads();

    const f32x4 zero4 = {0.f, 0.f, 0.f, 0.f};
    f32x4 acc[4][4];
#pragma unroll
    for (int i = 0; i < 4; ++i)
#pragma unroll
        for (int j = 0; j < 4; ++j) acc[i][j] = zero4;

#pragma unroll
    for (int ks = 0; ks < 4; ++ks) {
        const bf16x8* cur = (ks & 1) ? bwB : bwA;
        bf16x8*       nxt = (ks & 1) ? bwA : bwB;
        if (ks < 3) {
#pragma unroll
            for (int nf = 0; nf < 4; ++nf)
                nxt[nf] = okc[nf] ? *(const bf16x8*)(wp + (size_t)(nf * 16) * 128 + (ks + 1) * 32) : zrow;
        }
        bf16x8 af[4];
#pragma unroll
        for (int mf = 0; mf < 4; ++mf)
            af[mf] = *(const bf16x8*)&As[wm + mf*16 + lr][ks*32 + lg*8];
        __builtin_amdgcn_s_setprio(1);
#pragma unroll
        for (int mf = 0; mf < 4; ++mf)
#pragma unroll
            for (int nf = 0; nf < 4; ++nf)
                acc[mf][nf] = MFMA_BF16(af[mf], cur[nf], acc[mf][nf]);
        __builtin_amdgcn_s_setprio(0);
    }

#pragma unroll
    for (int half = 0; half < 2; ++half) {
        __syncthreads();
        if ((wid >> 1) == half) {
#pragma unroll
            for (int nf = 0; nf < 4; ++nf) {
                int col = wn + nf * 16 + lr;
                if (col >= 84) continue;
                float bv = (col < 81) ? bias[col] : 0.f;
#pragma unroll
                for (int mf = 0; mf < 4; ++mf)
#pragma unroll
                    for (int r = 0; r < 4; ++r) {
                        float vv = (col < 81) ? (acc[mf][nf][r] + bv) : 0.f;
                        Sb[mf * 16 + lg * 4 + r][col] = (bf16)vv;
                    }
            }
        }
        __syncthreads();
#pragma unroll
        for (int i = 0; i < 6; ++i) {
            int o = i * 256 + t;
            if (o < 64 * 21) {
                int row = o / 21, cq = (o - row * 21) * 4;
                *(bf16x4*)(outA + (size_t)(bm + half * 64 + row) * cAS + cq) =
                    *(const bf16x4*)&Sb[row][cq];
            }
        }
    }
}

// ---------------------------------------------------------------------------
// Generic k-loop GEMM, M=128: 1-barrier dbuf K-loop, bf16 residual stream.
// Sf overlays As/Bs (epilogue-only, barrier-separated).
// ---------------------------------------------------------------------------
template<bool OUTBF, bool RELU, bool RES, bool POS, bool LNOUT, bool TOUT>
__global__ __launch_bounds__(256) void k_gemm_res(const bf16* __restrict__ A,
                                                  const bf16* __restrict__ Wt,
                                                  const float* __restrict__ bias,
                                                  const bf16* __restrict__ resB,
                                                  bf16* __restrict__ outFB,
                                                  bf16* __restrict__ outB,
                                                  float* __restrict__ outT,
                                                  int K,
                                                  const float* __restrict__ ytab,
                                                  const float* __restrict__ xtab,
                                                  const float* __restrict__ lng,
                                                  const float* __restrict__ lnb,
                                                  bf16* __restrict__ xnbO)
{
    __shared__ __attribute__((aligned(16))) char smem[2 * 2 * 128 * 40 * sizeof(bf16)]; // 40960
    bf16 (*As)[128][40] = (bf16(*)[128][40])smem;             // [2][128][40], k-loop only
    bf16 (*Bs)[128][40] = (bf16(*)[128][40])(smem + 20480);   // [2][128][40], k-loop only
    float (*Sf)[136]    = (float(*)[136])smem;                // [64][136], epilogue only

    const int bm = blockIdx.x * 128;
    const int t = threadIdx.x;
    const int lane = t & 63, wid = t >> 6;
    const int wm = (wid >> 1) * 64, wn = (wid & 1) * 64;
    const int lr = lane & 15, lg = lane >> 4;

    const int r0 = t >> 2,          kg0 = (t & 3) * 8;
    const int r1 = (t + 256) >> 2,  kg1 = ((t + 256) & 3) * 8;

    const int nks = K >> 5;

    auto loadAW = [&](int k0, bf16x8* ra, bf16x8* rw) {
        ra[0] = *(const bf16x8*)(A  + (size_t)(bm + r0) * K + k0 + kg0);
        ra[1] = *(const bf16x8*)(A  + (size_t)(bm + r1) * K + k0 + kg1);
        rw[0] = *(const bf16x8*)(Wt + (size_t)r0 * K + k0 + kg0);
        rw[1] = *(const bf16x8*)(Wt + (size_t)r1 * K + k0 + kg1);
    };

    bf16x8 ra[2], rw[2];
    loadAW(0, ra, rw);
    *(bf16x8*)&As[0][r0][kg0] = ra[0];
    *(bf16x8*)&As[0][r1][kg1] = ra[1];
    *(bf16x8*)&Bs[0][r0][kg0] = rw[0];
    *(bf16x8*)&Bs[0][r1][kg1] = rw[1];
    if (nks > 1) loadAW(32, ra, rw);

    const f32x4 zero4 = {0.f, 0.f, 0.f, 0.f};
    f32x4 acc[4][4];
#pragma unroll
    for (int i = 0; i < 4; ++i)
#pragma unroll
        for (int j = 0; j < 4; ++j) acc[i][j] = zero4;

    for (int ks = 0; ks < nks; ++ks) {
        const int cur = ks & 1;
        __syncthreads();
        if (ks + 1 < nks) {
            *(bf16x8*)&As[cur ^ 1][r0][kg0] = ra[0];
            *(bf16x8*)&As[cur ^ 1][r1][kg1] = ra[1];
            *(bf16x8*)&Bs[cur ^ 1][r0][kg0] = rw[0];
            *(bf16x8*)&Bs[cur ^ 1][r1][kg1] = rw[1];
            if (ks + 2 < nks) loadAW((ks + 2) * 32, ra, rw);
        }
        bf16x8 af[4], bf[4];
#pragma unroll
        for (int mf = 0; mf < 4; ++mf)
            af[mf] = *(const bf16x8*)&As[cur][wm + mf*16 + lr][lg * 8];
#pragma unroll
        for (int nf = 0; nf < 4; ++nf)
            bf[nf] = *(const bf16x8*)&Bs[cur][wn + nf*16 + lr][lg * 8];
        __builtin_amdgcn_s_setprio(1);
#pragma unroll
        for (int mf = 0; mf < 4; ++mf)
#pragma unroll
            for (int nf = 0; nf < 4; ++nf)
                acc[mf][nf] = MFMA_BF16(af[mf], bf[nf], acc[mf][nf]);
        __builtin_amdgcn_s_setprio(0);
    }
    __syncthreads();

    if (OUTBF) {
        bf16 (*Sb)[136] = (bf16(*)[136])Sf;
#pragma unroll
        for (int nf = 0; nf < 4; ++nf) {
            int col = wn + nf * 16 + lr;
            float bv = bias ? bias[col] : 0.f;
#pragma unroll
            for (int mf = 0; mf < 4; ++mf)
#pragma unroll
                for (int r = 0; r < 4; ++r) {
                    float vv = acc[mf][nf][r] + bv;
                    if (RELU) vv = fmaxf(vv, 0.f);
                    Sb[wm + mf * 16 + lg * 4 + r][col] = (bf16)vv;
                }
        }
        __syncthreads();
#pragma unroll
        for (int i = 0; i < 8; ++i) {
            int o = i * 256 + t;
            int row = o >> 4, cg = (o & 15) * 8;
            *(bf16x8*)(outB + (size_t)(bm + row) * 128 + cg) = *(const bf16x8*)&Sb[row][cg];
        }
    } else {
        const int b_   = bm / cNPIX;
        const int hw0  = bm - b_ * cNPIX;
        for (int half = 0; half < 2; ++half) {
            __syncthreads();
            if ((wid >> 1) == half) {
#pragma unroll
                for (int nf = 0; nf < 4; ++nf) {
                    int col = wn + nf * 16 + lr;
                    float bv = bias ? bias[col] : 0.f;
#pragma unroll
                    for (int mf = 0; mf < 4; ++mf)
#pragma unroll
                        for (int r = 0; r < 4; ++r)
                            Sf[mf * 16 + lg * 4 + r][col] = acc[mf][nf][r] + bv;
                }
            }
            __syncthreads();
            if (!TOUT) {
#pragma unroll
                for (int i = 0; i < 8; ++i) {
                    int o = i * 256 + t;
                    int row = o >> 5, cq = (o & 31) * 4;
                    int grow = bm + half * 64 + row;
                    float4 v = *(const float4*)&Sf[row][cq];
                    if (POS) {
                        int hw = grow % cNPIX;
                        int h = hw / cW, w = hw - (hw / cW) * cW;
                        float4 p = (cq < 64) ? *(const float4*)(ytab + (h << 6) + cq)
                                             : *(const float4*)(xtab + (w << 6) + cq - 64);
                        v.x += p.x; v.y += p.y; v.z += p.z; v.w += p.w;
                    }
                    if (RES) {
                        bf16x4 rr = *(const bf16x4*)(resB + (size_t)grow * 128 + cq);
                        v.x += (float)rr[0]; v.y += (float)rr[1];
                        v.z += (float)rr[2]; v.w += (float)rr[3];
                    }
                    if (LNOUT) {
                        float s  = v.x + v.y + v.z + v.w;
                        float sq = v.x*v.x + v.y*v.y + v.z*v.z + v.w*v.w;
#pragma unroll
                        for (int mk = 1; mk < 32; mk <<= 1) {
                            s  += __shfl_xor(s,  mk);
                            sq += __shfl_xor(sq, mk);
                        }
                        float mu = s * (1.f / 128.f);
                        float rs = rsqrtf(sq * (1.f / 128.f) - mu * mu + 1e-5f);
                        float4 g4 = *(const float4*)(lng + cq);
                        float4 b4 = *(const float4*)(lnb + cq);
                        bf16x4 xo;
                        xo[0] = (bf16)((v.x - mu) * rs * g4.x + b4.x);
                        xo[1] = (bf16)((v.y - mu) * rs * g4.y + b4.y);
                        xo[2] = (bf16)((v.z - mu) * rs * g4.z + b4.z);
                        xo[3] = (bf16)((v.w - mu) * rs * g4.w + b4.w);
                        *(bf16x4*)(xnbO + (size_t)grow * 128 + cq) = xo;
                    }
                    bf16x4 fv;
                    fv[0] = (bf16)v.x; fv[1] = (bf16)v.y;
                    fv[2] = (bf16)v.z; fv[3] = (bf16)v.w;
                    *(bf16x4*)(outFB + (size_t)grow * 128 + cq) = fv;
                }
            } else {
#pragma unroll
                for (int i = 0; i < 8; ++i) {
                    int o = i * 256 + t;
                    int row = o >> 5, cq = (o & 31) * 4;
                    int grow = bm + half * 64 + row;
                    float4 v = *(const float4*)&Sf[row][cq];
                    bf16x4 rr = *(const bf16x4*)(resB + (size_t)grow * 128 + cq);
                    v.x += (float)rr[0]; v.y += (float)rr[1];
                    v.z += (float)rr[2]; v.w += (float)rr[3];
                    *(float4*)&Sf[row][cq] = v;
                }
                __syncthreads();
                const int lane16 = t & 15;
#pragma unroll
                for (int p = 0; p < 8; ++p) {
                    int col = p * 16 + (t >> 4);
                    float4 v;
                    v.x = Sf[lane16 * 4 + 0][col];
                    v.y = Sf[lane16 * 4 + 1][col];
                    v.z = Sf[lane16 * 4 + 2][col];
                    v.w = Sf[lane16 * 4 + 3][col];
                    *(float4*)(outT + ((size_t)(b_ * 128 + col)) * cNPIX
                               + hw0 + half * 64 + lane16 * 4) = v;
                }
            }
        }
    }
}

// ---------------------------------------------------------------------------
// Outlook fused gather (R14 structure: LDS-staged neighborhood).
// ---------------------------------------------------------------------------
__global__ __launch_bounds__(256) void k_olk_gather(const bf16* __restrict__ v,
                                                    const bf16* __restrict__ attn,
                                                    bf16* __restrict__ y)
{
    __shared__ bf16  Ls[100][136];
    __shared__ float pr[16][84];
    __shared__ float coef[16][26];

    const int t  = threadIdx.x;
    const int px = t >> 4;
    const int j  = t & 15;
    const int pix0 = blockIdx.x * 16;
    const int b   = pix0 / cNPIX;
    const int hw0 = pix0 % cNPIX;
    const int h   = hw0 / cW, w0 = hw0 % cW;
    const int pix = pix0 + px;
    const int w   = w0 + px;

    const size_t bbase = (size_t)b * cNPIX;

    for (int e = px; e < 100; e += 16) {
        const int a  = e / 20, cc = e - a * 20;
        const int sh = h + a - 2, sw = w0 + cc - 2;
        bf16x8 val;
        if ((unsigned)sh < (unsigned)cH && (unsigned)sw < (unsigned)cW) {
            val = *(const bf16x8*)(v + (bbase + (size_t)sh * cW + sw) * 128 + j * 8);
        } else {
#pragma unroll
            for (int q = 0; q < 8; ++q) val[q] = (bf16)0.f;
        }
        *(bf16x8*)&Ls[e][j * 8] = val;
    }

    if (j < 9) {
        const int p  = j;
        const int pi = p / 3, pj = p - pi * 3;
        const int hh = h + 1 - pi, ww = w + 1 - pj;
        float prv[9];
        if ((unsigned)hh < (unsigned)cH && (unsigned)ww < (unsigned)cW) {
            const size_t row = (size_t)(bbase + (size_t)hh * cW + ww);
            const bf16* arow = attn + row * cAS + p * 9;
            float lg[9];
            float m = 0.f;
#pragma unroll
            for (int q = 0; q < 9; ++q) { lg[q] = (float)arow[q]; m = fmaxf(m, lg[q]); }
            float se = 0.f;
#pragma unroll
            for (int q = 0; q < 9; ++q) { prv[q] = __expf(lg[q] - m); se += prv[q]; }
            float inv = 1.f / (se + __expf(-m));
#pragma unroll
            for (int q = 0; q < 9; ++q) prv[q] *= inv;
        } else {
#pragma unroll
            for (int q = 0; q < 9; ++q) prv[q] = 0.f;
        }
#pragma unroll
        for (int q = 0; q < 9; ++q) pr[px][p * 9 + q] = prv[q];
    }
    __syncthreads();

    for (int d = j; d < 25; d += 16) {
        const int a  = d / 5, bb = d - a * 5;
        float s = 0.f;
#pragma unroll
        for (int pi = 0; pi < 3; ++pi) {
            const int qi = pi + a - 2;
            if ((unsigned)qi >= 3u) continue;
#pragma unroll
            for (int pj = 0; pj < 3; ++pj) {
                const int qj = pj + bb - 2;
                if ((unsigned)qj >= 3u) continue;
                s += pr[px][(pi * 3 + pj) * 9 + qi * 3 + qj];
            }
        }
        coef[px][d] = s;
    }
    __syncthreads();

    float acc[8] = {};
#pragma unroll
    for (int a = 0; a < 5; ++a) {
#pragma unroll
        for (int bb = 0; bb < 5; ++bb) {
            const float cf = coef[px][a * 5 + bb];
            const bf16x8 v8 = *(const bf16x8*)&Ls[a * 20 + px + bb][j * 8];
#pragma unroll
            for (int e = 0; e < 8; ++e) acc[e] = fmaf(cf, (float)v8[e], acc[e]);
        }
    }
    bf16x8 o8;
#pragma unroll
    for (int e = 0; e < 8; ++e) o8[e] = (bf16)acc[e];
    *(bf16x8*)(y + (size_t)pix * 128 + j * 8) = o8;
}

// ---------------------------------------------------------------------------
// Depthwise 3x3 + bias + fast GELU.
// ---------------------------------------------------------------------------
__global__ __launch_bounds__(256) void k_dwconv_gelu(const bf16* __restrict__ h1,
                                                     const float* __restrict__ dwt,
                                                     const float* __restrict__ bdw,
                                                     bf16* __restrict__ h2)
{
    const int t   = threadIdx.x;
    const int c2  = t * 2;
    const int blk = blockIdx.x;
    const int row = blk >> 4;
    const int seg = blk & 15;
    const int bb  = row / cH, h = row % cH;
    const int w0  = seg * 20;

    float2 wgt[9];
#pragma unroll
    for (int k = 0; k < 9; ++k)
        wgt[k] = *(const float2*)(dwt + k * 512 + c2);
    if (h == 0) {
        wgt[0].x = wgt[0].y = wgt[1].x = wgt[1].y = wgt[2].x = wgt[2].y = 0.f;
    }
    if (h == cH - 1) {
        wgt[6].x = wgt[6].y = wgt[7].x = wgt[7].y = wgt[8].x = wgt[8].y = 0.f;
    }
    const float2 bias = *(const float2*)(bdw + c2);

    const size_t base = (size_t)bb * cNPIX;
    const int hm = (h == 0) ? 0 : h - 1;
    const int hp = (h == cH - 1) ? h : h + 1;
    const bf16* rp0 = h1 + (base + (size_t)hm * cW + w0) * 512 + c2;
    const bf16* rp1 = h1 + (base + (size_t)h  * cW + w0) * 512 + c2;
    const bf16* rp2 = h1 + (base + (size_t)hp * cW + w0) * 512 + c2;

    auto ldc = [&](const bf16* rp, int wofs) -> float2 {
        unsigned u = *(const unsigned*)(rp + (size_t)wofs * 512);
        float2 r;
        r.x = __uint_as_float(u << 16);
        r.y = __uint_as_float(u & 0xffff0000u);
        return r;
    };
    auto gelu = [](float x) -> float {
        float x2 = x * x;
        float z2 = fmaf(x2 * x, 0.0713548162726f, 1.5957691216057308f * x);
        float t1 = 1.f / (1.f + __expf(-z2));
        return x * t1;
    };

    float2 cm[3], c0[3], cp[3];
    if (seg == 0) {
#pragma unroll
        for (int r = 0; r < 3; ++r) { cm[r].x = 0.f; cm[r].y = 0.f; }
    } else {
        cm[0] = ldc(rp0, -1); cm[1] = ldc(rp1, -1); cm[2] = ldc(rp2, -1);
    }
    c0[0] = ldc(rp0, 0); c0[1] = ldc(rp1, 0); c0[2] = ldc(rp2, 0);

    bf16* op = h2 + (base + (size_t)h * cW + w0) * 512 + c2;

    for (int j = 0; j < 20; ++j) {
        if (j == 19 && seg == 15) {
#pragma unroll
            for (int r = 0; r < 3; ++r) { cp[r].x = 0.f; cp[r].y = 0.f; }
        } else {
            cp[0] = ldc(rp0, j + 1); cp[1] = ldc(rp1, j + 1); cp[2] = ldc(rp2, j + 1);
        }
        float a0 = bias.x, a1 = bias.y;
#pragma unroll
        for (int r = 0; r < 3; ++r) {
            a0 = fmaf(cm[r].x, wgt[r * 3 + 0].x, a0);
            a1 = fmaf(cm[r].y, wgt[r * 3 + 0].y, a1);
            a0 = fmaf(c0[r].x, wgt[r * 3 + 1].x, a0);
            a1 = fmaf(c0[r].y, wgt[r * 3 + 1].y, a1);
            a0 = fmaf(cp[r].x, wgt[r * 3 + 2].x, a0);
            a1 = fmaf(cp[r].y, wgt[r * 3 + 2].y, a1);
        }
        a0 = gelu(a0);
        a1 = gelu(a1);
        union { bf16 hh[2]; unsigned int u; } o2;
        o2.hh[0] = (bf16)a0;
        o2.hh[1] = (bf16)a1;
        *(unsigned int*)(op + (size_t)j * 512) = o2.u;
#pragma unroll
        for (int r = 0; r < 3; ++r) { cm[r] = c0[r]; c0[r] = cp[r]; }
    }
}

// ---------------------------------------------------------------------------
// Window attention (8-wave, dbuf, 1 barrier/tile).
// ---------------------------------------------------------------------------
template<bool SHIFT>
__global__ __launch_bounds__(512) void k_win_attn(const bf16* __restrict__ q,
                                                  const bf16* __restrict__ ks,
                                                  const bf16* __restrict__ vt,
                                                  bf16* __restrict__ out)
{
    __shared__ bf16 Ks[2][32][136];
    __shared__ bf16 Vs[2][128][44];
    __shared__ bf16 Ps[8][16][44];

    const int t = threadIdx.x, lane = t & 63, wid = t >> 6;
    const int lr = lane & 15, lg = lane >> 4;
    const int wb = blockIdx.x;
    const int b  = wb >> 6, win = wb & 63;
    const int nh = win >> 3, nw = win & 7;
    const int qbase = blockIdx.y * 128 + wid * 16;

    const float SCALE   = 0.088388347648318447f;
    const float MASKRAW = 100.f / 0.088388347648318447f;

    auto tokOf = [&](int p) {
        int ph = nh * 12 + p / 40;
        int pw = nw * 40 + (p % 40);
        if (SHIFT) {
            ph += 6;  if (ph >= cH) ph -= cH;
            pw += 20; if (pw >= cW) pw -= cW;
        }
        return b * cNPIX + ph * cW + pw;
    };

    int qp = min(qbase + lr, 479);
    const bf16* qptr = q + (size_t)tokOf(qp) * 128;
    bf16x8 qf[4];
#pragma unroll
    for (int c = 0; c < 4; ++c)
        qf[c] = *(const bf16x8*)(qptr + c * 32 + lg * 8);

    int labq[4];
    if (SHIFT) {
#pragma unroll
        for (int r = 0; r < 4; ++r) {
            int qrow = min(qbase + lg * 4 + r, 479);
            int qr = qrow / 40, qc = qrow - qr * 40;
            int rh = (nh == 7) ? (qr < 6 ? 1 : 2) : 0;
            int rc = (nw == 7) ? (qc < 20 ? 1 : 2) : 0;
            labq[r] = rh * 3 + rc;
        }
    }

    const bf16* kbase = ks + (size_t)wb * 480 * 128;
    const bf16* vbase = vt + (size_t)wb * 128 * 480;
    auto loadK = [&](int kt) {
        return *(const bf16x8*)(kbase + (size_t)(kt * 32 + (t >> 4)) * 128 + (t & 15) * 8);
    };
    auto loadV = [&](int kt) {
        return *(const bf16x8*)(vbase + (size_t)(t >> 2) * 480 + kt * 32 + (t & 3) * 8);
    };

    bf16x8 kreg = loadK(0);
    bf16x8 vreg = loadV(0);
    *(bf16x8*)&Ks[0][t >> 4][(t & 15) * 8] = kreg;
    *(bf16x8*)&Vs[0][t >> 2][(t & 3) * 8]  = vreg;
    kreg = loadK(1);
    vreg = loadV(1);

    int kc0 = lr, kr0 = 0;
    int kc1 = 16 + lr, kr1 = 0;

    const f32x4 zero4 = {0.f, 0.f, 0.f, 0.f};
    float m_run[4] = {0.f, 0.f, 0.f, 0.f};
    float mguard = 8.f;
    f32x4 l4 = zero4;
    f32x4 o[8];
#pragma unroll
    for (int nf = 0; nf < 8; ++nf) o[nf] = zero4;

    bf16x8 ones8;
#pragma unroll
    for (int j = 0; j < 8; ++j) ones8[j] = (bf16)1.f;

    for (int kt = 0; kt < 15; ++kt) {
        const int cur = kt & 1;
        __syncthreads();
        if (kt + 1 < 15) {
            *(bf16x8*)&Ks[cur ^ 1][t >> 4][(t & 15) * 8] = kreg;
            *(bf16x8*)&Vs[cur ^ 1][t >> 2][(t & 3) * 8]  = vreg;
            if (kt + 2 < 15) {
                kreg = loadK(kt + 2);
                vreg = loadV(kt + 2);
            }
        }

        f32x4 s0 = zero4, s1 = zero4;
        __builtin_amdgcn_s_setprio(1);
#pragma unroll
        for (int c = 0; c < 4; ++c) {
            bf16x8 kf0 = *(const bf16x8*)&Ks[cur][lr][c * 32 + lg * 8];
            bf16x8 kf1 = *(const bf16x8*)&Ks[cur][16 + lr][c * 32 + lg * 8];
            s0 = MFMA_BF16(qf[c], kf0, s0);
            s1 = MFMA_BF16(qf[c], kf1, s1);
        }
        __builtin_amdgcn_s_setprio(0);

        if (SHIFT) {
            int rh0 = (nh == 7) ? (kr0 < 6 ? 1 : 2) : 0;
            int rc0 = (nw == 7) ? (kc0 < 20 ? 1 : 2) : 0;
            int rh1 = (nh == 7) ? (kr1 < 6 ? 1 : 2) : 0;
            int rc1 = (nw == 7) ? (kc1 < 20 ? 1 : 2) : 0;
            int lab0 = rh0 * 3 + rc0;
            int lab1 = rh1 * 3 + rc1;
#pragma unroll
            for (int r = 0; r < 4; ++r) {
                if (labq[r] != lab0) s0[r] -= MASKRAW;
                if (labq[r] != lab1) s1[r] -= MASKRAW;
            }
        }
        kc0 += 32; if (kc0 >= 40) { kc0 -= 40; ++kr0; }
        kc1 += 32; if (kc1 >= 40) { kc1 -= 40; ++kr1; }

        float tm = fmaxf(fmaxf(fmaxf(s0[0], s0[1]), fmaxf(s0[2], s0[3])),
                         fmaxf(fmaxf(s1[0], s1[1]), fmaxf(s1[2], s1[3])));
        if (__any(tm * SCALE > mguard)) {
#pragma unroll
            for (int r = 0; r < 4; ++r) {
                float mx = fmaxf(s0[r], s1[r]);
#pragma unroll
                for (int off = 1; off < 16; off <<= 1) mx = fmaxf(mx, __shfl_xor(mx, off));
                float nm = fmaxf(m_run[r], mx * SCALE);
                float sc = __expf(m_run[r] - nm);
#pragma unroll
                for (int nf = 0; nf < 8; ++nf) o[nf][r] *= sc;
                l4[r] *= sc;
                m_run[r] = nm;
            }
            mguard = fminf(fminf(m_run[0], m_run[1]), fminf(m_run[2], m_run[3])) + 8.f;
        }

#pragma unroll
        for (int r = 0; r < 4; ++r) {
            float p0 = __expf(fmaf(s0[r], SCALE, -m_run[r]));
            float p1 = __expf(fmaf(s1[r], SCALE, -m_run[r]));
            Ps[wid][lg * 4 + r][lr]      = (bf16)p0;
            Ps[wid][lg * 4 + r][16 + lr] = (bf16)p1;
        }

        bf16x8 pa = *(const bf16x8*)&Ps[wid][lr][lg * 8];
        __builtin_amdgcn_s_setprio(1);
        l4 = MFMA_BF16(pa, ones8, l4);
#pragma unroll
        for (int nf = 0; nf < 8; ++nf) {
            bf16x8 bv = *(const bf16x8*)&Vs[cur][nf * 16 + lr][lg * 8];
            o[nf] = MFMA_BF16(pa, bv, o[nf]);
        }
        __builtin_amdgcn_s_setprio(0);
    }

#pragma unroll
    for (int r = 0; r < 4; ++r) {
        int qrow = qbase + lg * 4 + r;
        if (qrow >= 480) continue;
        float inv = 1.f / (l4[r] + __expf(-m_run[r]));
        size_t ooff = (size_t)tokOf(qrow) * 128;
#pragma unroll
        for (int nf = 0; nf < 8; ++nf)
            out[ooff + nf * 16 + lr] = (bf16)(o[nf][r] * inv);
    }
}

// ---------------------------------------------------------------------------
// Host launcher
// ---------------------------------------------------------------------------
extern "C" void kernel_launch(void* const* d_in, const int* in_sizes, int n_in,
                              void* d_out, int out_size, void* d_ws, size_t ws_size,
                              hipStream_t stream)
{
    (void)in_sizes; (void)n_in; (void)out_size; (void)ws_size;

    const float* X = (const float*)d_in[0];

    char* ws = (char*)d_ws;
    bf16*  f    = (bf16*)ws;                                  ws += (size_t)cNTOK * 128 * 2;
    bf16*  xnb  = (bf16*)ws;                                  ws += (size_t)cNTOK * 128 * 2;
    bf16*  bufA = (bf16*)ws;                                  ws += (size_t)cNTOK * 512 * 2;
    bf16*  bufB = (bf16*)ws;                                  ws += (size_t)cNTOK * 512 * 2;
    bf16*  wts  = (bf16*)ws;

    size_t wo_off = 0;
    auto nextw = [&](int K, int M) { bf16* p = wts + wo_off; wo_off += (size_t)K * M; return p; };
    bf16* agg_w1t = nextw(256, 128);
    bf16* agg_w2t = nextw(128, 128);
    bf16* ol_wvt  = nextw(128, 128);
    bf16* ol_wat  = nextw(128, 81);
    bf16* ol_wot  = nextw(128, 128);
    bf16* f1_w1t  = nextw(128, 512);
    bf16* f1_w2t  = nextw(512, 128);
    bf16* w_qkvt  = nextw(128, 384);
    bf16* w_wot   = nextw(128, 128);
    bf16* f2_w1t  = nextw(128, 512);
    bf16* f2_w2t  = nextw(512, 128);
    bf16* s_qkvt  = nextw(128, 384);
    bf16* s_wot   = nextw(128, 128);
    bf16* f3_w1t  = nextw(128, 512);
    bf16* f3_w2t  = nextw(512, 128);
    float* dwt1 = (float*)(wts + wo_off);
    float* dwt2 = dwt1 + 512 * 9;
    float* dwt3 = dwt2 + 512 * 9;
    float* ytab = dwt3 + 512 * 9;
    float* xtab = ytab + 96 * 64;

    WJobs jobs;
    int ji = 0;
    auto addj = [&](int src_idx, bf16* dst, int K, int M) {
        jobs.j[ji++] = WJob{(const float*)d_in[src_idx], dst, K, M};
    };
    addj(1,  agg_w1t, 256, 128);
    addj(3,  agg_w2t, 128, 128);
    addj(7,  ol_wvt,  128, 128);
    addj(8,  ol_wat,  128, 81);
    addj(10, ol_wot,  128, 128);
    addj(14, f1_w1t,  128, 512);
    addj(18, f1_w2t,  512, 128);
    addj(22, w_qkvt,           128, 128);
    addj(23, w_qkvt + 128*128, 128, 128);
    addj(24, w_qkvt + 256*128, 128, 128);
    addj(25, w_wot,   128, 128);
    addj(29, f2_w1t,  128, 512);
    addj(33, f2_w2t,  512, 128);
    addj(37, s_qkvt,           128, 128);
    addj(38, s_qkvt + 128*128, 128, 128);
    addj(39, s_qkvt + 256*128, 128, 128);
    addj(40, s_wot,   128, 128);
    addj(44, f3_w1t,  128, 512);
    addj(48, f3_w2t,  512, 128);
    k_wt<<<dim3(16, 16, 19), dim3(32, 8), 0, stream>>>(jobs);
    k_dwt<<<3, 256, 0, stream>>>((const float*)d_in[16], (const float*)d_in[31],
                                 (const float*)d_in[46], dwt1, dwt2, dwt3);
    k_postab<<<80, 256, 0, stream>>>(ytab, xtab);

    const int nTT = cNTOK / 128;   // 480 token tiles

    // ---- fused input-transpose + aggregation MLP (w2 epilogue emits ol-LN) --
    k_gemm_agg<<<nTT, 256, 0, stream>>>(X, agg_w1t, (const float*)d_in[2], bufB);
    k_gemm_res<false, false, false, false, true, false><<<nTT, 256, 0, stream>>>(
        bufB, agg_w2t, (const float*)d_in[4], nullptr, f, nullptr, nullptr, 128,
        nullptr, nullptr, (const float*)d_in[5], (const float*)d_in[6], xnb);

    // ---- outlook attention (ol_wo epilogue emits f1-LN) ----
    {
        bf16*  vb   = bufA;
        bf16*  gout = bufA + (size_t)cNTOK * 128;
        bf16*  atn  = bufB;
        k_gemm128<-1><<<nTT, 256, 0, stream>>>(xnb, ol_wvt, nullptr, vb, 128, nullptr, nullptr);
        k_gemm128_wa<<<nTT, 256, 0, stream>>>(xnb, ol_wat, (const float*)d_in[9], atn);
        k_olk_gather<<<cNTOK / 16, 256, 0, stream>>>(vb, atn, gout);
        k_gemm_res<false, false, true, false, true, false><<<nTT, 256, 0, stream>>>(
            gout, ol_wot, (const float*)d_in[11], f, f, nullptr, nullptr, 128,
            nullptr, nullptr, (const float*)d_in[12], (const float*)d_in[13], xnb);
    }

    // ---- conv FFN; w2 epilogue emits next block's LN (if lnG), or the
    //      transposed final output (f3) ----
    auto run_ffn = [&](int base, bf16* w1t, bf16* w2t, float* dwt, bool pos,
                       const float* lnG, const float* lnB, float* outT) {
        k_gemm128<-1><<<nTT * 4, 256, 0, stream>>>(
            xnb, w1t, (const float*)d_in[base + 3], bufA, 512, nullptr, nullptr);
        k_dwconv_gelu<<<cB * cH * 16, 256, 0, stream>>>(
            bufA, dwt, (const float*)d_in[base + 5], bufB);
        if (pos) {
            k_gemm_res<false, false, true, true, true, false><<<nTT, 256, 0, stream>>>(
                bufB, w2t, (const float*)d_in[base + 7], f, f, nullptr, nullptr, 512,
                ytab, xtab, lnG, lnB, xnb);
        } else if (lnG) {
            k_gemm_res<false, false, true, false, true, false><<<nTT, 256, 0, stream>>>(
                bufB, w2t, (const float*)d_in[base + 7], f, f, nullptr, nullptr, 512,
                nullptr, nullptr, lnG, lnB, xnb);
        } else {
            k_gemm_res<false, false, true, false, false, true><<<nTT, 256, 0, stream>>>(
                bufB, w2t, (const float*)d_in[base + 7], f, nullptr, nullptr, outT, 512,
                nullptr, nullptr, nullptr, nullptr, nullptr);
        }
    };

    // ---- window attention; wo epilogue emits next block's LN ----
    auto run_win = [&](int base, bf16* qkvt, bf16* wot, bool shift,
                       const float* lnG, const float* lnB) {
        bf16* qb  = bufA;
        bf16* ksb = bufA + (size_t)cNTOK * 128;
        bf16* vtb = bufA + (size_t)cNTOK * 256;
        bf16* ao  = bufB;
        if (shift)
            k_gemm128<1><<<nTT * 3, 256, 0, stream>>>(xnb, qkvt, nullptr, qb, 384, vtb, ksb);
        else
            k_gemm128<0><<<nTT * 3, 256, 0, stream>>>(xnb, qkvt, nullptr, qb, 384, vtb, ksb);
        if (shift) k_win_attn<true ><<<dim3(128, 4), 512, 0, stream>>>(qb, ksb, vtb, ao);
        else       k_win_attn<false><<<dim3(128, 4), 512, 0, stream>>>(qb, ksb, vtb, ao);
        k_gemm_res<false, false, true, false, true, false><<<nTT, 256, 0, stream>>>(
            ao, wot, (const float*)d_in[base + 6], f, f, nullptr, nullptr, 128,
            nullptr, nullptr, lnG, lnB, xnb);
    };

    run_ffn(12, f1_w1t, f1_w2t, dwt1, true,
            (const float*)d_in[20], (const float*)d_in[21], nullptr);   // f1
    run_win(20, w_qkvt, w_wot, false,
            (const float*)d_in[27], (const float*)d_in[28]);            // w
    run_ffn(27, f2_w1t, f2_w2t, dwt2, false,
            (const float*)d_in[35], (const float*)d_in[36], nullptr);   // f2
    run_win(35, s_qkvt, s_wot, true,
            (const float*)d_in[42], (const float*)d_in[43]);            // s
    run_ffn(42, f3_w1t, f3_w2t, dwt3, false, nullptr, nullptr,
            (float*)d_out);                                             // f3 -> d_out^T
}